// Round 1
// 1085.280 us; speedup vs baseline: 1.1222x; 1.1222x over previous
//
#include <hip/hip_runtime.h>
#include <hip/hip_bf16.h>

typedef __bf16 bf16;
typedef bf16 bf16x8 __attribute__((ext_vector_type(8)));
typedef bf16 bf16x4 __attribute__((ext_vector_type(4)));
typedef bf16 bf16x2 __attribute__((ext_vector_type(2)));
typedef float f32x4 __attribute__((ext_vector_type(4)));

#define MFMA16(a, b, c) __builtin_amdgcn_mfma_f32_16x16x32_bf16(a, b, c, 0, 0, 0)

constexpr int BB = 2, SS = 2048, DD = 4096, HH = 32, KVHH = 8, HDD = 128;
constexpr int QDIM = HH * HDD;     // 4096
constexpr int KVDIM = KVHH * HDD;  // 1024
constexpr int NQKV = QDIM + 2 * KVDIM;  // 6144
constexpr int LDX = NQKV;

__device__ inline void gload16(const bf16* g, bf16* l) {
    __builtin_amdgcn_global_load_lds((const __attribute__((address_space(1))) void*)g,
                                     (__attribute__((address_space(3))) void*)l, 16, 0, 0);
}

union U32BF2 { unsigned int u; bf16x2 v; };

// ---------------- fp32 -> bf16 convert (x) ----------------
__global__ __launch_bounds__(256) void cvt_bf16(const float* __restrict__ src,
                                                bf16* __restrict__ dst, int n4) {
    int i = blockIdx.x * 256 + threadIdx.x;
    if (i >= n4) return;
    float4 v = ((const float4*)src)[i];
    bf16x4 o;
    o[0] = (bf16)v.x; o[1] = (bf16)v.y; o[2] = (bf16)v.z; o[3] = (bf16)v.w;
    ((bf16x4*)dst)[i] = o;
}

// ---------------- weight transpose + fp32->bf16 ----------------
__global__ __launch_bounds__(256) void transpose_w(const float* __restrict__ src,
                                                   bf16* __restrict__ dst, int R, int C) {
    __shared__ bf16 t[32][33];
    int tx = threadIdx.x & 31, ty = threadIdx.x >> 5;
    int r0 = blockIdx.y * 32, c0 = blockIdx.x * 32;
#pragma unroll
    for (int i = 0; i < 4; i++)
        t[ty + i * 8][tx] = (bf16)src[(long)(r0 + ty + i * 8) * C + c0 + tx];
    __syncthreads();
#pragma unroll
    for (int i = 0; i < 4; i++)
        dst[(long)(c0 + ty + i * 8) * R + r0 + tx] = t[tx][ty + i * 8];
}

// ------------- V transpose from XQKV: Vt[((b*8+kvh)*128+hd)][pos] -------------
__global__ __launch_bounds__(256) void transpose_v(const bf16* __restrict__ XQKV,
                                                   bf16* __restrict__ Vt) {
    __shared__ bf16 t[32][33];
    int z = blockIdx.z, b = z >> 3, kvh = z & 7;
    int h0 = blockIdx.x * 32, p0 = blockIdx.y * 32;
    int tx = threadIdx.x & 31, ty = threadIdx.x >> 5;
#pragma unroll
    for (int i = 0; i < 4; i++)
        t[ty + i * 8][tx] = XQKV[(long)(b * SS + p0 + ty + i * 8) * LDX + QDIM + KVDIM +
                                 kvh * HDD + h0 + tx];
    __syncthreads();
#pragma unroll
    for (int i = 0; i < 4; i++)
        Vt[((long)(b * KVHH + kvh) * HDD + h0 + ty + i * 8) * SS + p0 + tx] =
            t[tx][ty + i * 8];
}

// ---- RoPE on Q section of XQKV, in place, uint-packed pairs ----
__global__ __launch_bounds__(256) void rope_q(bf16* __restrict__ X,
                                              const float* __restrict__ fc,
                                              const float* __restrict__ fs) {
    long t = (long)blockIdx.x * 256 + threadIdx.x;  // ((b*S+pos)*H + h)*64 + i2
    int i2 = (int)(t & 63);
    long u = t >> 6;
    int hh = (int)(u & 31);
    long bp = u >> 5;
    int pos = (int)(bp & (SS - 1));
    unsigned int* p = (unsigned int*)&X[bp * LDX + hh * HDD + 2 * i2];
    U32BF2 cv; cv.u = *p;
    float a = (float)cv.v[0], bb = (float)cv.v[1];
    float c = fc[pos * 64 + i2], s = fs[pos * 64 + i2];
    U32BF2 o;
    o.v[0] = (bf16)(a * c - bb * s);
    o.v[1] = (bf16)(a * s + bb * c);
    *p = o.u;
}

// ---- RoPE on K section of XQKV -> contiguous Kc[((b*8+kvh)*S+pos)*128+hd] ----
__global__ __launch_bounds__(256) void rope_kc(const bf16* __restrict__ X,
                                               const float* __restrict__ fc,
                                               const float* __restrict__ fs,
                                               bf16* __restrict__ Kc) {
    long t = (long)blockIdx.x * 256 + threadIdx.x;  // ((bk)*S+pos)*64 + i2
    int i2 = (int)(t & 63);
    long u = t >> 6;
    int pos = (int)(u & (SS - 1));
    int bk = (int)(u >> 11);
    int b = bk >> 3, kvh = bk & 7;
    const unsigned int* p =
        (const unsigned int*)&X[((long)(b * SS) + pos) * LDX + QDIM + kvh * HDD + 2 * i2];
    U32BF2 cv; cv.u = *p;
    float a = (float)cv.v[0], bb = (float)cv.v[1];
    float c = fc[pos * 64 + i2], s = fs[pos * 64 + i2];
    U32BF2 o;
    o.v[0] = (bf16)(a * c - bb * s);
    o.v[1] = (bf16)(a * s + bb * c);
    ((unsigned int*)Kc)[u * 64 + i2] = o.u;
}

// --------- suffix sums of V tiles from Vt: Suf[bk][t][hd] = sum_{j>=t*64} v_j ---------
__global__ __launch_bounds__(256) void sufv_k(const bf16* __restrict__ Vt,
                                              float* __restrict__ Suf) {
    __shared__ float ts[128][33];
    int bk = blockIdx.x;
    int hd = threadIdx.x & 127, tg = threadIdx.x >> 7;
    const bf16* row = Vt + ((long)bk * HDD + hd) * SS;
#pragma unroll
    for (int tt = 0; tt < 16; tt++) {
        int t = tg * 16 + tt;
        const bf16* p = row + t * 64;
        float s = 0.f;
#pragma unroll
        for (int j = 0; j < 8; j++) {
            bf16x8 v = *(const bf16x8*)&p[j * 8];
#pragma unroll
            for (int e = 0; e < 8; e++) s += (float)v[e];
        }
        ts[hd][t] = s;
    }
    __syncthreads();
    if (threadIdx.x < 128) {
        int h2 = threadIdx.x;
        float run = 0.f;
        Suf[((long)bk * 33 + 32) * HDD + h2] = 0.f;
        for (int t = 31; t >= 1; t--) {
            run += ts[h2][t];
            Suf[((long)bk * 33 + t) * HDD + h2] = run;
        }
    }
}

// ------- GEMM m97-style: C[MxN] = A[MxK]*B, BT = B^T (NxK), async LDS staging -------
template <typename CT>
__global__ __launch_bounds__(256) void gemm_bt(const bf16* __restrict__ A,
                                               const bf16* __restrict__ BT,
                                               CT* __restrict__ C, int M, int N, int K) {
    __shared__ bf16 As[128 * 32];
    __shared__ bf16 Bs[128 * 32];
    const int tid = threadIdx.x;
    const int lane = tid & 63, w = tid >> 6;
    const int quad = lane >> 4, lcol = lane & 15;
    const int m0 = blockIdx.y * 128, n0 = blockIdx.x * 128;
    const int wm = (w >> 1) * 64, wn = (w & 1) * 64;
    const int sr = tid >> 2;
    const int sc = (tid & 3) * 8;
    const bf16* ga = &A[(long)(m0 + sr) * K + sc];
    const bf16* gb = &BT[(long)(n0 + sr) * K + sc];
    bf16* lA = &As[w * 512];
    bf16* lB = &Bs[w * 512];
    f32x4 acc[4][4] = {};

    for (int k0 = 0; k0 < K; k0 += 32) {
        gload16(ga + k0, lA);
        gload16(ga + (long)64 * K + k0, lA + 2048);
        gload16(gb + k0, lB);
        gload16(gb + (long)64 * K + k0, lB + 2048);
        __syncthreads();
        bf16x8 af[4], bfr[4];
#pragma unroll
        for (int i = 0; i < 4; i++)
            af[i] = *(const bf16x8*)&As[(wm + i * 16 + lcol) * 32 + quad * 8];
#pragma unroll
        for (int j = 0; j < 4; j++)
            bfr[j] = *(const bf16x8*)&Bs[(wn + j * 16 + lcol) * 32 + quad * 8];
#pragma unroll
        for (int i = 0; i < 4; i++)
#pragma unroll
            for (int j = 0; j < 4; j++) acc[i][j] = MFMA16(af[i], bfr[j], acc[i][j]);
        __syncthreads();
    }
#pragma unroll
    for (int i = 0; i < 4; i++)
#pragma unroll
        for (int j = 0; j < 4; j++)
#pragma unroll
            for (int r = 0; r < 4; r++) {
                int row = m0 + wm + i * 16 + quad * 4 + r;
                int col = n0 + wn + j * 16 + lcol;
                C[(long)row * N + col] = (CT)acc[i][j][r];
            }
}

// -------- attention v3: paired q-chunks (qc, 15-qc) per block => uniform 34 tiles --------
// grid = dim3(8, H, B); 512 blocks = exactly the 2-blocks/CU residency limit, so all
// blocks are resident from t=0 and the work-imbalance tail is eliminated.
__global__ __launch_bounds__(256) void attn_k(const bf16* __restrict__ XQKV,
                                              const bf16* __restrict__ Kc,
                                              const bf16* __restrict__ Vt,
                                              const float* __restrict__ Suf,
                                              bf16* __restrict__ AO) {
    __shared__ bf16 Ks[64 * 128];       // 16B-slot swizzled
    __shared__ bf16 Vs[128 * 64];       // 16B-slot swizzled
    __shared__ bf16 Pl[4][2][16 * 72];  // per-wave P round-trip
    const int tid = threadIdx.x;
    const int lane = tid & 63, w = tid >> 6;
    const int quad = lane >> 4, lcol = lane & 15;
    const int h = blockIdx.y, b = blockIdx.z;
    const int kvh = h >> 2;
    const float c2 = 0.08838834764831845f * 1.4426950408889634f;  // 1/sqrt(128)*log2(e)

    const bf16* KcB = Kc + (long)((b * KVHH + kvh) * SS) * HDD;
    const bf16* VtB = Vt + (long)((b * KVHH + kvh) * HDD) * SS;

    for (int rep = 0; rep < 2; rep++) {
        // pair heavy chunk with light chunk: NT sums to 34 for every block
        const int qc = rep == 0 ? 15 - (int)blockIdx.x : (int)blockIdx.x;
        const int qbase = qc * 128 + w * 32;
        const int NT = 2 * qc + 2;  // block-uniform causal tile count

        bf16x8 qf[2][4];
#pragma unroll
        for (int rf = 0; rf < 2; rf++)
#pragma unroll
            for (int kc = 0; kc < 4; kc++)
                qf[rf][kc] = *(const bf16x8*)&XQKV[((long)(b * SS) + qbase + rf * 16 + lcol) * LDX +
                                                   h * HDD + kc * 32 + quad * 8];
        f32x4 oacc[2][8] = {};
        float m2[2][4], l[2][4];
#pragma unroll
        for (int rf = 0; rf < 2; rf++)
#pragma unroll
            for (int r = 0; r < 4; r++) { m2[rf][r] = -1e30f; l[rf][r] = 0.f; }

        for (int kt = 0; kt < NT; kt++) {
            const int kb0 = kt * 64;
            // stage K tile (64 pos x 128 hd), swizzle: phys chunk = c ^ (p&7)
#pragma unroll
            for (int i = 0; i < 4; i++) {
                int j = i * 256 + tid;
                int p = j >> 4, cp = j & 15, c = cp ^ (p & 7);
                gload16(KcB + (long)(kb0 + p) * HDD + c * 8, &Ks[j * 8]);
            }
            // stage V tile (128 hd x 64 pos), swizzle: phys chunk = c ^ (r&7)
#pragma unroll
            for (int i = 0; i < 4; i++) {
                int j = i * 256 + tid;
                int r = j >> 3, cp = j & 7, c = cp ^ (r & 7);
                gload16(VtB + (long)r * SS + kb0 + c * 8, &Vs[j * 8]);
            }
            __syncthreads();
            // QK^T
            f32x4 sa[2][4] = {};
#pragma unroll
            for (int ch = 0; ch < 4; ch++) {
                bf16x8 kf[4];
                int p = ch * 16 + lcol;
#pragma unroll
                for (int kc = 0; kc < 4; kc++) {
                    int c = kc * 4 + quad;
                    kf[kc] = *(const bf16x8*)&Ks[(p * 16 + (c ^ (p & 7))) * 8];
                }
#pragma unroll
                for (int rf = 0; rf < 2; rf++)
#pragma unroll
                    for (int kc = 0; kc < 4; kc++)
                        sa[rf][ch] = MFMA16(qf[rf][kc], kf[kc], sa[rf][ch]);
            }
            // online softmax (multiplicative mask: future -> score exactly 0, stays in softmax)
            float alpha[2][4];
#pragma unroll
            for (int rf = 0; rf < 2; rf++)
#pragma unroll
                for (int r = 0; r < 4; r++) {
                    int qpos = qbase + rf * 16 + quad * 4 + r;
                    float mt = -3e38f;
#pragma unroll
                    for (int ch = 0; ch < 4; ch++) {
                        float s = (kb0 + ch * 16 + lcol > qpos) ? 0.f : sa[rf][ch][r] * c2;
                        sa[rf][ch][r] = s;  // store masked score, avoid recompute below
                        mt = fmaxf(mt, s);
                    }
#pragma unroll
                    for (int off = 1; off < 16; off <<= 1) mt = fmaxf(mt, __shfl_xor(mt, off, 64));
                    float mnew = fmaxf(m2[rf][r], mt);
                    alpha[rf][r] = exp2f(m2[rf][r] - mnew);
                    float rs = 0.f;
#pragma unroll
                    for (int ch = 0; ch < 4; ch++) {
                        float e = exp2f(sa[rf][ch][r] - mnew);
                        rs += e;
                        Pl[w][rf][(quad * 4 + r) * 72 + ch * 16 + lcol] = (bf16)e;
                    }
#pragma unroll
                    for (int off = 1; off < 16; off <<= 1) rs += __shfl_xor(rs, off, 64);
                    l[rf][r] = l[rf][r] * alpha[rf][r] + rs;
                    m2[rf][r] = mnew;
                }
            // P: per-wave LDS roundtrip C-layout -> A-layout (no barrier needed)
            bf16x8 pf[2][2];
#pragma unroll
            for (int rf = 0; rf < 2; rf++)
#pragma unroll
                for (int k2 = 0; k2 < 2; k2++)
                    pf[rf][k2] = *(const bf16x8*)&Pl[w][rf][lcol * 72 + k2 * 32 + quad * 8];
            // PV
#pragma unroll
            for (int nj = 0; nj < 8; nj++) {
                int r = nj * 16 + lcol;
                bf16x8 vf0 = *(const bf16x8*)&Vs[(r * 8 + (quad ^ (r & 7))) * 8];
                bf16x8 vf1 = *(const bf16x8*)&Vs[(r * 8 + ((4 + quad) ^ (r & 7))) * 8];
#pragma unroll
                for (int rf = 0; rf < 2; rf++) {
                    f32x4 o = oacc[rf][nj];
#pragma unroll
                    for (int rr = 0; rr < 4; rr++) o[rr] *= alpha[rf][rr];
                    o = MFMA16(pf[rf][0], vf0, o);
                    o = MFMA16(pf[rf][1], vf1, o);
                    oacc[rf][nj] = o;
                }
            }
            __syncthreads();
        }
        // epilogue: strictly-future masked keys (score 0 -> weight 2^-mf each) via V suffix sums
        const int cnt = SS - NT * 64;
        const float* sufp = &Suf[((long)((b * KVHH + kvh) * 33) + NT) * HDD];
#pragma unroll
        for (int rf = 0; rf < 2; rf++) {
            float so[4], sm[4], rz[4];
#pragma unroll
            for (int r = 0; r < 4; r++) {
                float mf = (cnt > 0) ? fmaxf(m2[rf][r], 0.f) : m2[rf][r];
                so[r] = exp2f(m2[rf][r] - mf);
                sm[r] = exp2f(-mf);
                rz[r] = 1.f / (l[rf][r] * so[r] + (float)cnt * sm[r]);
            }
#pragma unroll
            for (int nj = 0; nj < 8; nj++) {
                float suf = sufp[nj * 16 + lcol];
#pragma unroll
                for (int r = 0; r < 4; r++) {
                    float o = (oacc[rf][nj][r] * so[r] + sm[r] * suf) * rz[r];
                    AO[((long)(b * SS) + qbase + rf * 16 + quad * 4 + r) * QDIM + h * HDD +
                       nj * 16 + lcol] = (bf16)o;
                }
            }
        }
    }
}

extern "C" void kernel_launch(void* const* d_in, const int* in_sizes, int n_in,
                              void* d_out, int out_size, void* d_ws, size_t ws_size,
                              hipStream_t stream) {
    const float* x  = (const float*)d_in[0];
    const float* fc = (const float*)d_in[1];
    const float* fs = (const float*)d_in[2];
    const float* wq = (const float*)d_in[4];
    const float* wk = (const float*)d_in[5];
    const float* wv = (const float*)d_in[6];
    const float* wo = (const float*)d_in[7];
    float* out = (float*)d_out;

    char* ws = (char*)d_ws;
    bf16* Wt   = (bf16*)ws; ws += (long)NQKV * DD * 2;             // 50.3 MB
    bf16* woT  = (bf16*)ws; ws += (long)DD * QDIM * 2;             // 33.6 MB
    bf16* XQKV = (bf16*)ws; ws += (long)BB * SS * NQKV * 2;        // 50.3 MB
    bf16* Vt   = (bf16*)ws; ws += (long)BB * KVHH * HDD * SS * 2;  // 8.4 MB
    bf16* Xb   = (bf16*)ws; ws += (long)BB * SS * DD * 2;          // 33.6 MB
    float* Suf = (float*)ws; ws += (long)BB * KVHH * 33 * HDD * 4; // 270 KB
    bf16* AO = Xb;            // Xb dead after QKV gemm
    bf16* Kc = Wt;            // Wt dead after QKV gemm (8.4 MB needed)

    const int M = BB * SS;  // 4096

    cvt_bf16<<<(DD * M / 4 + 255) / 256, 256, 0, stream>>>(x, Xb, DD * M / 4);

    transpose_w<<<dim3(QDIM / 32, DD / 32), 256, 0, stream>>>(wq, Wt, DD, QDIM);
    transpose_w<<<dim3(KVDIM / 32, DD / 32), 256, 0, stream>>>(wk, Wt + (long)QDIM * DD, DD, KVDIM);
    transpose_w<<<dim3(KVDIM / 32, DD / 32), 256, 0, stream>>>(wv, Wt + (long)(QDIM + KVDIM) * DD, DD, KVDIM);
    transpose_w<<<dim3(DD / 32, QDIM / 32), 256, 0, stream>>>(wo, woT, QDIM, DD);

    gemm_bt<bf16><<<dim3(NQKV / 128, M / 128), 256, 0, stream>>>(Xb, Wt, XQKV, M, NQKV, DD);

    rope_q<<<(int)(((long)BB * SS * HH * 64) / 256), 256, 0, stream>>>(XQKV, fc, fs);
    rope_kc<<<(int)(((long)BB * KVHH * SS * 64) / 256), 256, 0, stream>>>(XQKV, fc, fs, Kc);

    transpose_v<<<dim3(HDD / 32, SS / 32, BB * KVHH), 256, 0, stream>>>(XQKV, Vt);
    sufv_k<<<BB * KVHH, 256, 0, stream>>>(Vt, Suf);

    attn_k<<<dim3(8, HH, BB), 256, 0, stream>>>(XQKV, Kc, Vt, Suf, AO);

    gemm_bt<float><<<dim3(DD / 128, M / 128), 256, 0, stream>>>(AO, woT, out, M, DD, QDIM);
}

// Round 2
// 1049.047 us; speedup vs baseline: 1.1609x; 1.0345x over previous
//
#include <hip/hip_runtime.h>
#include <hip/hip_bf16.h>

typedef __bf16 bf16;
typedef bf16 bf16x8 __attribute__((ext_vector_type(8)));
typedef bf16 bf16x4 __attribute__((ext_vector_type(4)));
typedef bf16 bf16x2 __attribute__((ext_vector_type(2)));
typedef float f32x4 __attribute__((ext_vector_type(4)));

#define MFMA16(a, b, c) __builtin_amdgcn_mfma_f32_16x16x32_bf16(a, b, c, 0, 0, 0)

constexpr int BB = 2, SS = 2048, DD = 4096, HH = 32, KVHH = 8, HDD = 128;
constexpr int QDIM = HH * HDD;     // 4096
constexpr int KVDIM = KVHH * HDD;  // 1024
constexpr int NQKV = QDIM + 2 * KVDIM;  // 6144
constexpr int LDX = NQKV;

__device__ inline void gload16(const bf16* g, bf16* l) {
    __builtin_amdgcn_global_load_lds((const __attribute__((address_space(1))) void*)g,
                                     (__attribute__((address_space(3))) void*)l, 16, 0, 0);
}

union U32BF2 { unsigned int u; bf16x2 v; };

// ---------------- fp32 -> bf16 convert (x) ----------------
__global__ __launch_bounds__(256) void cvt_bf16(const float* __restrict__ src,
                                                bf16* __restrict__ dst, int n4) {
    int i = blockIdx.x * 256 + threadIdx.x;
    if (i >= n4) return;
    float4 v = ((const float4*)src)[i];
    bf16x4 o;
    o[0] = (bf16)v.x; o[1] = (bf16)v.y; o[2] = (bf16)v.z; o[3] = (bf16)v.w;
    ((bf16x4*)dst)[i] = o;
}

// ---------------- weight transpose + fp32->bf16 ----------------
__global__ __launch_bounds__(256) void transpose_w(const float* __restrict__ src,
                                                   bf16* __restrict__ dst, int R, int C) {
    __shared__ bf16 t[32][33];
    int tx = threadIdx.x & 31, ty = threadIdx.x >> 5;
    int r0 = blockIdx.y * 32, c0 = blockIdx.x * 32;
#pragma unroll
    for (int i = 0; i < 4; i++)
        t[ty + i * 8][tx] = (bf16)src[(long)(r0 + ty + i * 8) * C + c0 + tx];
    __syncthreads();
#pragma unroll
    for (int i = 0; i < 4; i++)
        dst[(long)(c0 + ty + i * 8) * R + r0 + tx] = t[tx][ty + i * 8];
}

// ------------- V transpose from XQKV: Vt[((b*8+kvh)*128+hd)][pos] -------------
__global__ __launch_bounds__(256) void transpose_v(const bf16* __restrict__ XQKV,
                                                   bf16* __restrict__ Vt) {
    __shared__ bf16 t[32][33];
    int z = blockIdx.z, b = z >> 3, kvh = z & 7;
    int h0 = blockIdx.x * 32, p0 = blockIdx.y * 32;
    int tx = threadIdx.x & 31, ty = threadIdx.x >> 5;
#pragma unroll
    for (int i = 0; i < 4; i++)
        t[ty + i * 8][tx] = XQKV[(long)(b * SS + p0 + ty + i * 8) * LDX + QDIM + KVDIM +
                                 kvh * HDD + h0 + tx];
    __syncthreads();
#pragma unroll
    for (int i = 0; i < 4; i++)
        Vt[((long)(b * KVHH + kvh) * HDD + h0 + ty + i * 8) * SS + p0 + tx] =
            t[tx][ty + i * 8];
}

// ---- RoPE on Q section of XQKV, in place, uint-packed pairs ----
// NOTE: folds the attention scale 1/sqrt(128)*log2(e) into Q here, so QK^T
// scores come out of the MFMA pre-scaled (saves a v_mul per score in attn_k).
__global__ __launch_bounds__(256) void rope_q(bf16* __restrict__ X,
                                              const float* __restrict__ fc,
                                              const float* __restrict__ fs) {
    const float c2 = 0.08838834764831845f * 1.4426950408889634f;
    long t = (long)blockIdx.x * 256 + threadIdx.x;  // ((b*S+pos)*H + h)*64 + i2
    int i2 = (int)(t & 63);
    long u = t >> 6;
    int hh = (int)(u & 31);
    long bp = u >> 5;
    int pos = (int)(bp & (SS - 1));
    unsigned int* p = (unsigned int*)&X[bp * LDX + hh * HDD + 2 * i2];
    U32BF2 cv; cv.u = *p;
    float a = (float)cv.v[0], bb = (float)cv.v[1];
    float c = fc[pos * 64 + i2], s = fs[pos * 64 + i2];
    U32BF2 o;
    o.v[0] = (bf16)((a * c - bb * s) * c2);
    o.v[1] = (bf16)((a * s + bb * c) * c2);
    *p = o.u;
}

// ---- RoPE on K section of XQKV -> contiguous Kc[((b*8+kvh)*S+pos)*128+hd] ----
__global__ __launch_bounds__(256) void rope_kc(const bf16* __restrict__ X,
                                               const float* __restrict__ fc,
                                               const float* __restrict__ fs,
                                               bf16* __restrict__ Kc) {
    long t = (long)blockIdx.x * 256 + threadIdx.x;  // ((bk)*S+pos)*64 + i2
    int i2 = (int)(t & 63);
    long u = t >> 6;
    int pos = (int)(u & (SS - 1));
    int bk = (int)(u >> 11);
    int b = bk >> 3, kvh = bk & 7;
    const unsigned int* p =
        (const unsigned int*)&X[((long)(b * SS) + pos) * LDX + QDIM + kvh * HDD + 2 * i2];
    U32BF2 cv; cv.u = *p;
    float a = (float)cv.v[0], bb = (float)cv.v[1];
    float c = fc[pos * 64 + i2], s = fs[pos * 64 + i2];
    U32BF2 o;
    o.v[0] = (bf16)(a * c - bb * s);
    o.v[1] = (bf16)(a * s + bb * c);
    ((unsigned int*)Kc)[u * 64 + i2] = o.u;
}

// --------- suffix sums of V tiles from Vt: Suf[bk][t][hd] = sum_{j>=t*64} v_j ---------
__global__ __launch_bounds__(256) void sufv_k(const bf16* __restrict__ Vt,
                                              float* __restrict__ Suf) {
    __shared__ float ts[128][33];
    int bk = blockIdx.x;
    int hd = threadIdx.x & 127, tg = threadIdx.x >> 7;
    const bf16* row = Vt + ((long)bk * HDD + hd) * SS;
#pragma unroll
    for (int tt = 0; tt < 16; tt++) {
        int t = tg * 16 + tt;
        const bf16* p = row + t * 64;
        float s = 0.f;
#pragma unroll
        for (int j = 0; j < 8; j++) {
            bf16x8 v = *(const bf16x8*)&p[j * 8];
#pragma unroll
            for (int e = 0; e < 8; e++) s += (float)v[e];
        }
        ts[hd][t] = s;
    }
    __syncthreads();
    if (threadIdx.x < 128) {
        int h2 = threadIdx.x;
        float run = 0.f;
        Suf[((long)bk * 33 + 32) * HDD + h2] = 0.f;
        for (int t = 31; t >= 1; t--) {
            run += ts[h2][t];
            Suf[((long)bk * 33 + t) * HDD + h2] = run;
        }
    }
}

// ------- GEMM m97-style: C[MxN] = A[MxK]*B, BT = B^T (NxK), async LDS staging -------
template <typename CT>
__global__ __launch_bounds__(256) void gemm_bt(const bf16* __restrict__ A,
                                               const bf16* __restrict__ BT,
                                               CT* __restrict__ C, int M, int N, int K) {
    __shared__ bf16 As[128 * 32];
    __shared__ bf16 Bs[128 * 32];
    const int tid = threadIdx.x;
    const int lane = tid & 63, w = tid >> 6;
    const int quad = lane >> 4, lcol = lane & 15;
    const int m0 = blockIdx.y * 128, n0 = blockIdx.x * 128;
    const int wm = (w >> 1) * 64, wn = (w & 1) * 64;
    const int sr = tid >> 2;
    const int sc = (tid & 3) * 8;
    const bf16* ga = &A[(long)(m0 + sr) * K + sc];
    const bf16* gb = &BT[(long)(n0 + sr) * K + sc];
    bf16* lA = &As[w * 512];
    bf16* lB = &Bs[w * 512];
    f32x4 acc[4][4] = {};

    for (int k0 = 0; k0 < K; k0 += 32) {
        gload16(ga + k0, lA);
        gload16(ga + (long)64 * K + k0, lA + 2048);
        gload16(gb + k0, lB);
        gload16(gb + (long)64 * K + k0, lB + 2048);
        __syncthreads();
        bf16x8 af[4], bfr[4];
#pragma unroll
        for (int i = 0; i < 4; i++)
            af[i] = *(const bf16x8*)&As[(wm + i * 16 + lcol) * 32 + quad * 8];
#pragma unroll
        for (int j = 0; j < 4; j++)
            bfr[j] = *(const bf16x8*)&Bs[(wn + j * 16 + lcol) * 32 + quad * 8];
#pragma unroll
        for (int i = 0; i < 4; i++)
#pragma unroll
            for (int j = 0; j < 4; j++) acc[i][j] = MFMA16(af[i], bfr[j], acc[i][j]);
        __syncthreads();
    }
#pragma unroll
    for (int i = 0; i < 4; i++)
#pragma unroll
        for (int j = 0; j < 4; j++)
#pragma unroll
            for (int r = 0; r < 4; r++) {
                int row = m0 + wm + i * 16 + quad * 4 + r;
                int col = n0 + wn + j * 16 + lcol;
                C[(long)row * N + col] = (CT)acc[i][j][r];
            }
}

// -------- attention v4: paired q-chunks + double-buffered K/V pipeline --------
// grid = dim3(8, H, B); 512 blocks, uniform 34 tiles. Per tile (T3 2-phase recipe):
//   STAGE(buf^1, t+1) ; compute(buf) ; s_waitcnt vmcnt(0) ; s_barrier
// One barrier per tile; stage latency hides under compute. Pl shrunk to a single
// per-wave 16x72 buffer (sequential rf reuse) so LDS = 73.7KB -> 2 blocks/CU.
__global__ __launch_bounds__(256) void attn_k(const bf16* __restrict__ XQKV,
                                              const bf16* __restrict__ Kc,
                                              const bf16* __restrict__ Vt,
                                              const float* __restrict__ Suf,
                                              bf16* __restrict__ AO) {
    __shared__ bf16 Ks[2][64 * 128];    // 16B-slot swizzled, double-buffered
    __shared__ bf16 Vs[2][128 * 64];    // 16B-slot swizzled, double-buffered
    __shared__ bf16 Pl[4][16 * 72];     // per-wave P round-trip (rf-sequential)
    const int tid = threadIdx.x;
    const int lane = tid & 63, w = tid >> 6;
    const int quad = lane >> 4, lcol = lane & 15;
    const int h = blockIdx.y, b = blockIdx.z;
    const int kvh = h >> 2;

    const bf16* KcB = Kc + (long)((b * KVHH + kvh) * SS) * HDD;
    const bf16* VtB = Vt + (long)((b * KVHH + kvh) * HDD) * SS;

    // stage helper: K tile (64 pos x 128 hd) + V tile (128 hd x 64 pos), swizzled
    auto stageKV = [&](int buf, int kt2) {
        const int kb0s = kt2 * 64;
        bf16* ksb = &Ks[buf][0];
        bf16* vsb = &Vs[buf][0];
#pragma unroll
        for (int i = 0; i < 4; i++) {
            int j = i * 256 + tid;
            int p = j >> 4, cp = j & 15, c = cp ^ (p & 7);
            gload16(KcB + (long)(kb0s + p) * HDD + c * 8, &ksb[j * 8]);
        }
#pragma unroll
        for (int i = 0; i < 4; i++) {
            int j = i * 256 + tid;
            int r = j >> 3, cp = j & 7, c = cp ^ (r & 7);
            gload16(VtB + (long)r * SS + kb0s + c * 8, &vsb[j * 8]);
        }
    };

    for (int rep = 0; rep < 2; rep++) {
        // pair heavy chunk with light chunk: NT sums to 34 for every block
        const int qc = rep == 0 ? 15 - (int)blockIdx.x : (int)blockIdx.x;
        const int qbase = qc * 128 + w * 32;
        const int NT = 2 * qc + 2;  // block-uniform causal tile count (even)

        bf16x8 qf[2][4];
#pragma unroll
        for (int rf = 0; rf < 2; rf++)
#pragma unroll
            for (int kc = 0; kc < 4; kc++)
                qf[rf][kc] = *(const bf16x8*)&XQKV[((long)(b * SS) + qbase + rf * 16 + lcol) * LDX +
                                                   h * HDD + kc * 32 + quad * 8];
        f32x4 oacc[2][8] = {};
        float m2[2][4], l[2][4];
#pragma unroll
        for (int rf = 0; rf < 2; rf++)
#pragma unroll
            for (int r = 0; r < 4; r++) { m2[rf][r] = -1e30f; l[rf][r] = 0.f; }

        // prologue: stage tile 0, drain, barrier
        stageKV(0, 0);
        asm volatile("s_waitcnt vmcnt(0)" ::: "memory");
        __builtin_amdgcn_s_barrier();

        int cur = 0;
        for (int kt = 0; kt < NT; kt++) {
            const int kb0 = kt * 64;
            // issue next-tile stage into the other buffer (clamped re-stage on last)
            const int nxt = (kt + 1 < NT) ? kt + 1 : kt;
            stageKV(cur ^ 1, nxt);

            const bf16* KsC = &Ks[cur][0];
            const bf16* VsC = &Vs[cur][0];
            // QK^T (Q pre-scaled by 1/sqrt(128)*log2e in rope_q)
            f32x4 sa[2][4] = {};
#pragma unroll
            for (int ch = 0; ch < 4; ch++) {
                bf16x8 kf[4];
                int p = ch * 16 + lcol;
#pragma unroll
                for (int kc = 0; kc < 4; kc++) {
                    int c = kc * 4 + quad;
                    kf[kc] = *(const bf16x8*)&KsC[(p * 16 + (c ^ (p & 7))) * 8];
                }
#pragma unroll
                for (int rf = 0; rf < 2; rf++)
#pragma unroll
                    for (int kc = 0; kc < 4; kc++)
                        sa[rf][ch] = MFMA16(qf[rf][kc], kf[kc], sa[rf][ch]);
            }
            // causal mask (multiplicative: future -> score exactly 0) — only needed
            // on tiles that touch the diagonal; wave-uniform skip otherwise.
            const bool needMask = (kb0 + 63 > qbase);
            if (needMask) {
#pragma unroll
                for (int rf = 0; rf < 2; rf++)
#pragma unroll
                    for (int ch = 0; ch < 4; ch++) {
                        int col = kb0 + ch * 16 + lcol;
#pragma unroll
                        for (int r = 0; r < 4; r++) {
                            int qpos = qbase + rf * 16 + quad * 4 + r;
                            if (col > qpos) sa[rf][ch][r] = 0.f;
                        }
                    }
            }
            // online softmax: max reduce per row; l kept as PER-LANE partial
            // (alpha is lane-uniform, so the 16-lane sum-reduce is deferred to epilogue)
            float alpha[2][4];
            bf16x8 pf[2][2];
#pragma unroll
            for (int rf = 0; rf < 2; rf++) {
#pragma unroll
                for (int r = 0; r < 4; r++) {
                    float mt = fmaxf(fmaxf(sa[rf][0][r], sa[rf][1][r]),
                                     fmaxf(sa[rf][2][r], sa[rf][3][r]));
#pragma unroll
                    for (int off = 1; off < 16; off <<= 1)
                        mt = fmaxf(mt, __shfl_xor(mt, off, 64));
                    float mnew = fmaxf(m2[rf][r], mt);
                    alpha[rf][r] = exp2f(m2[rf][r] - mnew);
                    float rs = 0.f;
#pragma unroll
                    for (int ch = 0; ch < 4; ch++) {
                        float e = exp2f(sa[rf][ch][r] - mnew);
                        rs += e;
                        Pl[w][(quad * 4 + r) * 72 + ch * 16 + lcol] = (bf16)e;
                    }
                    l[rf][r] = l[rf][r] * alpha[rf][r] + rs;  // lane-partial
                    m2[rf][r] = mnew;
                }
                // per-wave LDS roundtrip C-layout -> A-layout (same-wave lgkm ordering)
#pragma unroll
                for (int k2 = 0; k2 < 2; k2++)
                    pf[rf][k2] = *(const bf16x8*)&Pl[w][lcol * 72 + k2 * 32 + quad * 8];
            }
            // PV
#pragma unroll
            for (int nj = 0; nj < 8; nj++) {
                int r = nj * 16 + lcol;
                bf16x8 vf0 = *(const bf16x8*)&VsC[(r * 8 + (quad ^ (r & 7))) * 8];
                bf16x8 vf1 = *(const bf16x8*)&VsC[(r * 8 + ((4 + quad) ^ (r & 7))) * 8];
#pragma unroll
                for (int rf = 0; rf < 2; rf++) {
                    f32x4 o = oacc[rf][nj];
#pragma unroll
                    for (int rr = 0; rr < 4; rr++) o[rr] *= alpha[rf][rr];
                    o = MFMA16(pf[rf][0], vf0, o);
                    o = MFMA16(pf[rf][1], vf1, o);
                    oacc[rf][nj] = o;
                }
            }
            // end-of-tile: wait the prefetch (covered by this tile's compute), barrier
            asm volatile("s_waitcnt vmcnt(0)" ::: "memory");
            __builtin_amdgcn_s_barrier();
            cur ^= 1;
        }
        // deferred 16-lane l reduction (once per rep instead of per tile)
#pragma unroll
        for (int rf = 0; rf < 2; rf++)
#pragma unroll
            for (int r = 0; r < 4; r++)
#pragma unroll
                for (int off = 1; off < 16; off <<= 1)
                    l[rf][r] += __shfl_xor(l[rf][r], off, 64);
        // epilogue: strictly-future masked keys (score 0 -> weight 2^-mf each) via V suffix sums
        const int cnt = SS - NT * 64;
        const float* sufp = &Suf[((long)((b * KVHH + kvh) * 33) + NT) * HDD];
#pragma unroll
        for (int rf = 0; rf < 2; rf++) {
            float so[4], sm[4], rz[4];
#pragma unroll
            for (int r = 0; r < 4; r++) {
                float mf = (cnt > 0) ? fmaxf(m2[rf][r], 0.f) : m2[rf][r];
                so[r] = exp2f(m2[rf][r] - mf);
                sm[r] = exp2f(-mf);
                rz[r] = 1.f / (l[rf][r] * so[r] + (float)cnt * sm[r]);
            }
#pragma unroll
            for (int nj = 0; nj < 8; nj++) {
                float suf = sufp[nj * 16 + lcol];
#pragma unroll
                for (int r = 0; r < 4; r++) {
                    float o = (oacc[rf][nj][r] * so[r] + sm[r] * suf) * rz[r];
                    AO[((long)(b * SS) + qbase + rf * 16 + quad * 4 + r) * QDIM + h * HDD +
                       nj * 16 + lcol] = (bf16)o;
                }
            }
        }
    }
}

extern "C" void kernel_launch(void* const* d_in, const int* in_sizes, int n_in,
                              void* d_out, int out_size, void* d_ws, size_t ws_size,
                              hipStream_t stream) {
    const float* x  = (const float*)d_in[0];
    const float* fc = (const float*)d_in[1];
    const float* fs = (const float*)d_in[2];
    const float* wq = (const float*)d_in[4];
    const float* wk = (const float*)d_in[5];
    const float* wv = (const float*)d_in[6];
    const float* wo = (const float*)d_in[7];
    float* out = (float*)d_out;

    char* ws = (char*)d_ws;
    bf16* Wt   = (bf16*)ws; ws += (long)NQKV * DD * 2;             // 50.3 MB
    bf16* woT  = (bf16*)ws; ws += (long)DD * QDIM * 2;             // 33.6 MB
    bf16* XQKV = (bf16*)ws; ws += (long)BB * SS * NQKV * 2;        // 50.3 MB
    bf16* Vt   = (bf16*)ws; ws += (long)BB * KVHH * HDD * SS * 2;  // 8.4 MB
    bf16* Xb   = (bf16*)ws; ws += (long)BB * SS * DD * 2;          // 33.6 MB
    float* Suf = (float*)ws; ws += (long)BB * KVHH * 33 * HDD * 4; // 270 KB
    bf16* AO = Xb;            // Xb dead after QKV gemm
    bf16* Kc = Wt;            // Wt dead after QKV gemm (8.4 MB needed)

    const int M = BB * SS;  // 4096

    cvt_bf16<<<(DD * M / 4 + 255) / 256, 256, 0, stream>>>(x, Xb, DD * M / 4);

    transpose_w<<<dim3(QDIM / 32, DD / 32), 256, 0, stream>>>(wq, Wt, DD, QDIM);
    transpose_w<<<dim3(KVDIM / 32, DD / 32), 256, 0, stream>>>(wk, Wt + (long)QDIM * DD, DD, KVDIM);
    transpose_w<<<dim3(KVDIM / 32, DD / 32), 256, 0, stream>>>(wv, Wt + (long)(QDIM + KVDIM) * DD, DD, KVDIM);
    transpose_w<<<dim3(DD / 32, QDIM / 32), 256, 0, stream>>>(wo, woT, QDIM, DD);

    gemm_bt<bf16><<<dim3(NQKV / 128, M / 128), 256, 0, stream>>>(Xb, Wt, XQKV, M, NQKV, DD);

    rope_q<<<(int)(((long)BB * SS * HH * 64) / 256), 256, 0, stream>>>(XQKV, fc, fs);
    rope_kc<<<(int)(((long)BB * KVHH * SS * 64) / 256), 256, 0, stream>>>(XQKV, fc, fs, Kc);

    transpose_v<<<dim3(HDD / 32, SS / 32, BB * KVHH), 256, 0, stream>>>(XQKV, Vt);
    sufv_k<<<BB * KVHH, 256, 0, stream>>>(Vt, Suf);

    attn_k<<<dim3(8, HH, BB), 256, 0, stream>>>(XQKV, Kc, Vt, Suf, AO);

    gemm_bt<float><<<dim3(DD / 128, M / 128), 256, 0, stream>>>(AO, woT, out, M, DD, QDIM);
}

// Round 3
// 926.441 us; speedup vs baseline: 1.3146x; 1.1323x over previous
//
#include <hip/hip_runtime.h>
#include <hip/hip_bf16.h>

typedef __bf16 bf16;
typedef bf16 bf16x8 __attribute__((ext_vector_type(8)));
typedef bf16 bf16x4 __attribute__((ext_vector_type(4)));
typedef bf16 bf16x2 __attribute__((ext_vector_type(2)));
typedef float f32x4 __attribute__((ext_vector_type(4)));

#define MFMA16(a, b, c) __builtin_amdgcn_mfma_f32_16x16x32_bf16(a, b, c, 0, 0, 0)

constexpr int BB = 2, SS = 2048, DD = 4096, HH = 32, KVHH = 8, HDD = 128;
constexpr int QDIM = HH * HDD;     // 4096
constexpr int KVDIM = KVHH * HDD;  // 1024
constexpr int NQKV = QDIM + 2 * KVDIM;  // 6144
constexpr int LDX = NQKV;

__device__ inline void gload16(const bf16* g, bf16* l) {
    __builtin_amdgcn_global_load_lds((const __attribute__((address_space(1))) void*)g,
                                     (__attribute__((address_space(3))) void*)l, 16, 0, 0);
}

union U32BF2 { unsigned int u; bf16x2 v; };

// ---------------- fp32 -> bf16 convert (x) ----------------
__global__ __launch_bounds__(256) void cvt_bf16(const float* __restrict__ src,
                                                bf16* __restrict__ dst, int n4) {
    int i = blockIdx.x * 256 + threadIdx.x;
    if (i >= n4) return;
    float4 v = ((const float4*)src)[i];
    bf16x4 o;
    o[0] = (bf16)v.x; o[1] = (bf16)v.y; o[2] = (bf16)v.z; o[3] = (bf16)v.w;
    ((bf16x4*)dst)[i] = o;
}

// ---------------- weight transpose + fp32->bf16 ----------------
__global__ __launch_bounds__(256) void transpose_w(const float* __restrict__ src,
                                                   bf16* __restrict__ dst, int R, int C) {
    __shared__ bf16 t[32][33];
    int tx = threadIdx.x & 31, ty = threadIdx.x >> 5;
    int r0 = blockIdx.y * 32, c0 = blockIdx.x * 32;
#pragma unroll
    for (int i = 0; i < 4; i++)
        t[ty + i * 8][tx] = (bf16)src[(long)(r0 + ty + i * 8) * C + c0 + tx];
    __syncthreads();
#pragma unroll
    for (int i = 0; i < 4; i++)
        dst[(long)(c0 + ty + i * 8) * R + r0 + tx] = t[tx][ty + i * 8];
}

// ------------- V transpose from XQKV: Vt[((b*8+kvh)*128+hd)][pos] -------------
__global__ __launch_bounds__(256) void transpose_v(const bf16* __restrict__ XQKV,
                                                   bf16* __restrict__ Vt) {
    __shared__ bf16 t[32][33];
    int z = blockIdx.z, b = z >> 3, kvh = z & 7;
    int h0 = blockIdx.x * 32, p0 = blockIdx.y * 32;
    int tx = threadIdx.x & 31, ty = threadIdx.x >> 5;
#pragma unroll
    for (int i = 0; i < 4; i++)
        t[ty + i * 8][tx] = XQKV[(long)(b * SS + p0 + ty + i * 8) * LDX + QDIM + KVDIM +
                                 kvh * HDD + h0 + tx];
    __syncthreads();
#pragma unroll
    for (int i = 0; i < 4; i++)
        Vt[((long)(b * KVHH + kvh) * HDD + h0 + ty + i * 8) * SS + p0 + tx] =
            t[tx][ty + i * 8];
}

// ---- RoPE on Q section of XQKV, in place, uint-packed pairs ----
// NOTE: folds the attention scale 1/sqrt(128)*log2(e) into Q here, so QK^T
// scores come out of the MFMA pre-scaled (saves a v_mul per score in attn_k).
__global__ __launch_bounds__(256) void rope_q(bf16* __restrict__ X,
                                              const float* __restrict__ fc,
                                              const float* __restrict__ fs) {
    const float c2 = 0.08838834764831845f * 1.4426950408889634f;
    long t = (long)blockIdx.x * 256 + threadIdx.x;  // ((b*S+pos)*H + h)*64 + i2
    int i2 = (int)(t & 63);
    long u = t >> 6;
    int hh = (int)(u & 31);
    long bp = u >> 5;
    int pos = (int)(bp & (SS - 1));
    unsigned int* p = (unsigned int*)&X[bp * LDX + hh * HDD + 2 * i2];
    U32BF2 cv; cv.u = *p;
    float a = (float)cv.v[0], bb = (float)cv.v[1];
    float c = fc[pos * 64 + i2], s = fs[pos * 64 + i2];
    U32BF2 o;
    o.v[0] = (bf16)((a * c - bb * s) * c2);
    o.v[1] = (bf16)((a * s + bb * c) * c2);
    *p = o.u;
}

// ---- RoPE on K section of XQKV -> contiguous Kc[((b*8+kvh)*S+pos)*128+hd] ----
__global__ __launch_bounds__(256) void rope_kc(const bf16* __restrict__ X,
                                               const float* __restrict__ fc,
                                               const float* __restrict__ fs,
                                               bf16* __restrict__ Kc) {
    long t = (long)blockIdx.x * 256 + threadIdx.x;  // ((bk)*S+pos)*64 + i2
    int i2 = (int)(t & 63);
    long u = t >> 6;
    int pos = (int)(u & (SS - 1));
    int bk = (int)(u >> 11);
    int b = bk >> 3, kvh = bk & 7;
    const unsigned int* p =
        (const unsigned int*)&X[((long)(b * SS) + pos) * LDX + QDIM + kvh * HDD + 2 * i2];
    U32BF2 cv; cv.u = *p;
    float a = (float)cv.v[0], bb = (float)cv.v[1];
    float c = fc[pos * 64 + i2], s = fs[pos * 64 + i2];
    U32BF2 o;
    o.v[0] = (bf16)(a * c - bb * s);
    o.v[1] = (bf16)(a * s + bb * c);
    ((unsigned int*)Kc)[u * 64 + i2] = o.u;
}

// --------- suffix sums of V tiles from Vt: Suf[bk][t][hd] = sum_{j>=t*64} v_j ---------
__global__ __launch_bounds__(256) void sufv_k(const bf16* __restrict__ Vt,
                                              float* __restrict__ Suf) {
    __shared__ float ts[128][33];
    int bk = blockIdx.x;
    int hd = threadIdx.x & 127, tg = threadIdx.x >> 7;
    const bf16* row = Vt + ((long)bk * HDD + hd) * SS;
#pragma unroll
    for (int tt = 0; tt < 16; tt++) {
        int t = tg * 16 + tt;
        const bf16* p = row + t * 64;
        float s = 0.f;
#pragma unroll
        for (int j = 0; j < 8; j++) {
            bf16x8 v = *(const bf16x8*)&p[j * 8];
#pragma unroll
            for (int e = 0; e < 8; e++) s += (float)v[e];
        }
        ts[hd][t] = s;
    }
    __syncthreads();
    if (threadIdx.x < 128) {
        int h2 = threadIdx.x;
        float run = 0.f;
        Suf[((long)bk * 33 + 32) * HDD + h2] = 0.f;
        for (int t = 31; t >= 1; t--) {
            run += ts[h2][t];
            Suf[((long)bk * 33 + t) * HDD + h2] = run;
        }
    }
}

// ------- GEMM m97-style: C[MxN] = A[MxK]*B, BT = B^T (NxK), async LDS staging -------
template <typename CT>
__global__ __launch_bounds__(256) void gemm_bt(const bf16* __restrict__ A,
                                               const bf16* __restrict__ BT,
                                               CT* __restrict__ C, int M, int N, int K) {
    __shared__ bf16 As[128 * 32];
    __shared__ bf16 Bs[128 * 32];
    const int tid = threadIdx.x;
    const int lane = tid & 63, w = tid >> 6;
    const int quad = lane >> 4, lcol = lane & 15;
    const int m0 = blockIdx.y * 128, n0 = blockIdx.x * 128;
    const int wm = (w >> 1) * 64, wn = (w & 1) * 64;
    const int sr = tid >> 2;
    const int sc = (tid & 3) * 8;
    const bf16* ga = &A[(long)(m0 + sr) * K + sc];
    const bf16* gb = &BT[(long)(n0 + sr) * K + sc];
    bf16* lA = &As[w * 512];
    bf16* lB = &Bs[w * 512];
    f32x4 acc[4][4] = {};

    for (int k0 = 0; k0 < K; k0 += 32) {
        gload16(ga + k0, lA);
        gload16(ga + (long)64 * K + k0, lA + 2048);
        gload16(gb + k0, lB);
        gload16(gb + (long)64 * K + k0, lB + 2048);
        __syncthreads();
        bf16x8 af[4], bfr[4];
#pragma unroll
        for (int i = 0; i < 4; i++)
            af[i] = *(const bf16x8*)&As[(wm + i * 16 + lcol) * 32 + quad * 8];
#pragma unroll
        for (int j = 0; j < 4; j++)
            bfr[j] = *(const bf16x8*)&Bs[(wn + j * 16 + lcol) * 32 + quad * 8];
#pragma unroll
        for (int i = 0; i < 4; i++)
#pragma unroll
            for (int j = 0; j < 4; j++) acc[i][j] = MFMA16(af[i], bfr[j], acc[i][j]);
        __syncthreads();
    }
#pragma unroll
    for (int i = 0; i < 4; i++)
#pragma unroll
        for (int j = 0; j < 4; j++)
#pragma unroll
            for (int r = 0; r < 4; r++) {
                int row = m0 + wm + i * 16 + quad * 4 + r;
                int col = n0 + wn + j * 16 + lcol;
                C[(long)row * N + col] = (CT)acc[i][j][r];
            }
}

// -------- attention v5: 8 waves x 16 q-rows, swapped QK^T, in-register softmax --------
// grid = dim3(8, H, B), block = 512. Paired chunks (15-bx, bx): uniform 34 tiles/block.
// Swapped MFMA (A=K, B=Q) -> S^T[kv][q]: each lane owns one q-row (q = lcol), 16 kv
// scores in registers; softmax stats are per-lane scalars (2 shuffles for cross-quad
// max, l-sum deferred to epilogue). LDS = 32K (K dbuf) + 32K (V dbuf) + 16K (Pl)
// = exactly 80KB -> 2 blocks/CU; __launch_bounds__(512,4) -> 4 waves/SIMD.
__global__ __launch_bounds__(512, 4) void attn_k(const bf16* __restrict__ XQKV,
                                                 const bf16* __restrict__ Kc,
                                                 const bf16* __restrict__ Vt,
                                                 const float* __restrict__ Suf,
                                                 bf16* __restrict__ AO) {
    __shared__ bf16 Ks[2][64 * 128];    // 16B-slot swizzled, double-buffered
    __shared__ bf16 Vs[2][128 * 64];    // 16B-slot swizzled, double-buffered
    __shared__ bf16 Pl[8][16 * 64];     // per-wave P roundtrip, XOR-swizzled rows
    const int tid = threadIdx.x;
    const int lane = tid & 63, w = tid >> 6;       // w in 0..7
    const int quad = lane >> 4, lcol = lane & 15;
    const int h = blockIdx.y, b = blockIdx.z;
    const int kvh = h >> 2;

    const bf16* KcB = Kc + (long)((b * KVHH + kvh) * SS) * HDD;
    const bf16* VtB = Vt + (long)((b * KVHH + kvh) * HDD) * SS;

    // thread-constant staging offsets (1024 16B-slots each for K and V, 512 threads)
    int kofs[2], vofs[2];
#pragma unroll
    for (int i = 0; i < 2; i++) {
        int j = i * 512 + tid;
        int p = j >> 4, cp = j & 15, c = cp ^ (p & 7);
        kofs[i] = p * HDD + c * 8;
        int r = j >> 3, cp2 = j & 7, cv = cp2 ^ (r & 7);
        vofs[i] = r * SS + cv * 8;
    }

    auto stageKV = [&](int buf, int kb0s) {
        bf16* ksb = &Ks[buf][0];
        bf16* vsb = &Vs[buf][0];
#pragma unroll
        for (int i = 0; i < 2; i++)
            gload16(KcB + (long)kb0s * HDD + kofs[i], &ksb[(i * 512 + tid) * 8]);
#pragma unroll
        for (int i = 0; i < 2; i++)
            gload16(VtB + (long)kb0s + vofs[i], &vsb[(i * 512 + tid) * 8]);
    };

    for (int rep = 0; rep < 2; rep++) {
        // pair heavy chunk with light chunk: NT sums to 34 for every block
        const int qc = rep == 0 ? 15 - (int)blockIdx.x : (int)blockIdx.x;
        const int qbase = qc * 128 + w * 16;
        const int NT = 2 * qc + 2;  // block-uniform causal tile count
        const int qpos = qbase + lcol;  // this lane's q-row

        bf16x8 qf[4];
#pragma unroll
        for (int kc = 0; kc < 4; kc++)
            qf[kc] = *(const bf16x8*)&XQKV[((long)(b * SS) + qbase + lcol) * LDX +
                                           h * HDD + kc * 32 + quad * 8];
        f32x4 oacc[8] = {};
        float m2 = -1e30f, l = 0.f;

        // prologue: stage tile 0, drain, barrier
        stageKV(0, 0);
        asm volatile("s_waitcnt vmcnt(0)" ::: "memory");
        __builtin_amdgcn_s_barrier();

        int cur = 0;
        for (int kt = 0; kt < NT; kt++) {
            const int kb0 = kt * 64;
            stageKV(cur ^ 1, (kt + 1 < NT ? kt + 1 : kt) * 64);

            const bf16* KsC = &Ks[cur][0];
            const bf16* VsC = &Vs[cur][0];
            // swapped QK^T: sa[ch] = S^T[kv = ch*16+quad*4+reg][q = qbase+lcol]
            f32x4 sa[4] = {};
            __builtin_amdgcn_s_setprio(1);
#pragma unroll
            for (int ch = 0; ch < 4; ch++) {
                int p = ch * 16 + lcol;
#pragma unroll
                for (int kc = 0; kc < 4; kc++) {
                    int c = kc * 4 + quad;
                    bf16x8 kf = *(const bf16x8*)&KsC[(p * 16 + (c ^ (p & 7))) * 8];
                    sa[ch] = MFMA16(kf, qf[kc], sa[ch]);
                }
            }
            __builtin_amdgcn_s_setprio(0);
            // causal mask (multiplicative: future -> score exactly 0); wave-uniform skip
            if (kb0 + 63 > qbase) {
#pragma unroll
                for (int ch = 0; ch < 4; ch++)
#pragma unroll
                    for (int r = 0; r < 4; r++)
                        if (kb0 + ch * 16 + quad * 4 + r > qpos) sa[ch][r] = 0.f;
            }
            // in-register online softmax: per-lane q-row stats
            f32x4 mx = sa[0];
#pragma unroll
            for (int ch = 1; ch < 4; ch++)
#pragma unroll
                for (int r = 0; r < 4; r++) mx[r] = fmaxf(mx[r], sa[ch][r]);
            float mt = fmaxf(fmaxf(mx[0], mx[1]), fmaxf(mx[2], mx[3]));
            mt = fmaxf(mt, __shfl_xor(mt, 16, 64));
            mt = fmaxf(mt, __shfl_xor(mt, 32, 64));
            float mnew = fmaxf(m2, mt);
            float alpha = exp2f(m2 - mnew);
            m2 = mnew;
            float rs = 0.f;
            const int xm = (lcol & 7) << 3;
            bf16* plw = &Pl[w][0];
#pragma unroll
            for (int ch = 0; ch < 4; ch++) {
                bf16x4 pv;
#pragma unroll
                for (int r = 0; r < 4; r++) {
                    float e = exp2f(sa[ch][r] - mnew);
                    rs += e;
                    pv[r] = (bf16)e;
                }
                *(bf16x4*)&plw[lcol * 64 + ((ch * 16 + quad * 4) ^ xm)] = pv;
            }
            l = l * alpha + rs;  // lane-partial over this quad's kv subset
            // read back in PV A-layout: pf[k2][j] = P[q=lcol][kv = k2*32+quad*8+j]
            bf16x8 pf0 = *(const bf16x8*)&plw[lcol * 64 + ((quad * 8) ^ xm)];
            bf16x8 pf1 = *(const bf16x8*)&plw[lcol * 64 + ((32 + quad * 8) ^ xm)];
            // alpha for the PV C-layout rows (q = quad*4+r): pull from lane lcol'=quad*4+r
            float a4[4];
#pragma unroll
            for (int r = 0; r < 4; r++)
                a4[r] = __shfl(alpha, (quad << 4) | (quad * 4 + r), 64);
            // PV
            __builtin_amdgcn_s_setprio(1);
#pragma unroll
            for (int nj = 0; nj < 8; nj++) {
                int rr = nj * 16 + lcol;
                bf16x8 vf0 = *(const bf16x8*)&VsC[(rr * 8 + (quad ^ (rr & 7))) * 8];
                bf16x8 vf1 = *(const bf16x8*)&VsC[(rr * 8 + ((4 + quad) ^ (rr & 7))) * 8];
                f32x4 o = oacc[nj];
#pragma unroll
                for (int r = 0; r < 4; r++) o[r] *= a4[r];
                o = MFMA16(pf0, vf0, o);
                o = MFMA16(pf1, vf1, o);
                oacc[nj] = o;
            }
            __builtin_amdgcn_s_setprio(0);
            // end-of-tile: wait the prefetch (covered by this tile's compute), barrier
            asm volatile("s_waitcnt vmcnt(0)" ::: "memory");
            __builtin_amdgcn_s_barrier();
            cur ^= 1;
        }
        // finalize per-row stats: cross-quad l sum (deferred), then redistribute
        l += __shfl_xor(l, 16, 64);
        l += __shfl_xor(l, 32, 64);
        const int cnt = SS - NT * 64;
        float mf = (cnt > 0) ? fmaxf(m2, 0.f) : m2;
        float so = exp2f(m2 - mf);
        float sm = exp2f(-mf);
        float rz = 1.f / (l * so + (float)cnt * sm);
        float so4[4], sm4[4], rz4[4];
#pragma unroll
        for (int r = 0; r < 4; r++) {
            int src = (quad << 4) | (quad * 4 + r);
            so4[r] = __shfl(so, src, 64);
            sm4[r] = __shfl(sm, src, 64);
            rz4[r] = __shfl(rz, src, 64);
        }
        // epilogue: strictly-future keys beyond NT*64 (score 0 -> weight 2^-mf) via V suffix sums
        const float* sufp = &Suf[((long)((b * KVHH + kvh) * 33) + NT) * HDD];
#pragma unroll
        for (int nj = 0; nj < 8; nj++) {
            float suf = sufp[nj * 16 + lcol];
#pragma unroll
            for (int r = 0; r < 4; r++) {
                float o = (oacc[nj][r] * so4[r] + sm4[r] * suf) * rz4[r];
                AO[((long)(b * SS) + qbase + quad * 4 + r) * QDIM + h * HDD +
                   nj * 16 + lcol] = (bf16)o;
            }
        }
    }
}

extern "C" void kernel_launch(void* const* d_in, const int* in_sizes, int n_in,
                              void* d_out, int out_size, void* d_ws, size_t ws_size,
                              hipStream_t stream) {
    const float* x  = (const float*)d_in[0];
    const float* fc = (const float*)d_in[1];
    const float* fs = (const float*)d_in[2];
    const float* wq = (const float*)d_in[4];
    const float* wk = (const float*)d_in[5];
    const float* wv = (const float*)d_in[6];
    const float* wo = (const float*)d_in[7];
    float* out = (float*)d_out;

    char* ws = (char*)d_ws;
    bf16* Wt   = (bf16*)ws; ws += (long)NQKV * DD * 2;             // 50.3 MB
    bf16* woT  = (bf16*)ws; ws += (long)DD * QDIM * 2;             // 33.6 MB
    bf16* XQKV = (bf16*)ws; ws += (long)BB * SS * NQKV * 2;        // 50.3 MB
    bf16* Vt   = (bf16*)ws; ws += (long)BB * KVHH * HDD * SS * 2;  // 8.4 MB
    bf16* Xb   = (bf16*)ws; ws += (long)BB * SS * DD * 2;          // 33.6 MB
    float* Suf = (float*)ws; ws += (long)BB * KVHH * 33 * HDD * 4; // 270 KB
    bf16* AO = Xb;            // Xb dead after QKV gemm
    bf16* Kc = Wt;            // Wt dead after QKV gemm (8.4 MB needed)

    const int M = BB * SS;  // 4096

    cvt_bf16<<<(DD * M / 4 + 255) / 256, 256, 0, stream>>>(x, Xb, DD * M / 4);

    transpose_w<<<dim3(QDIM / 32, DD / 32), 256, 0, stream>>>(wq, Wt, DD, QDIM);
    transpose_w<<<dim3(KVDIM / 32, DD / 32), 256, 0, stream>>>(wk, Wt + (long)QDIM * DD, DD, KVDIM);
    transpose_w<<<dim3(KVDIM / 32, DD / 32), 256, 0, stream>>>(wv, Wt + (long)(QDIM + KVDIM) * DD, DD, KVDIM);
    transpose_w<<<dim3(DD / 32, QDIM / 32), 256, 0, stream>>>(wo, woT, QDIM, DD);

    gemm_bt<bf16><<<dim3(NQKV / 128, M / 128), 256, 0, stream>>>(Xb, Wt, XQKV, M, NQKV, DD);

    rope_q<<<(int)(((long)BB * SS * HH * 64) / 256), 256, 0, stream>>>(XQKV, fc, fs);
    rope_kc<<<(int)(((long)BB * KVHH * SS * 64) / 256), 256, 0, stream>>>(XQKV, fc, fs, Kc);

    transpose_v<<<dim3(HDD / 32, SS / 32, BB * KVHH), 256, 0, stream>>>(XQKV, Vt);
    sufv_k<<<BB * KVHH, 256, 0, stream>>>(Vt, Suf);

    attn_k<<<dim3(8, HH, BB), 512, 0, stream>>>(XQKV, Kc, Vt, Suf, AO);

    gemm_bt<float><<<dim3(DD / 128, M / 128), 256, 0, stream>>>(AO, woT, out, M, DD, QDIM);
}

// Round 4
// 837.634 us; speedup vs baseline: 1.4540x; 1.1060x over previous
//
#include <hip/hip_runtime.h>
#include <hip/hip_bf16.h>

typedef __bf16 bf16;
typedef bf16 bf16x8 __attribute__((ext_vector_type(8)));
typedef bf16 bf16x4 __attribute__((ext_vector_type(4)));
typedef bf16 bf16x2 __attribute__((ext_vector_type(2)));
typedef float f32x4 __attribute__((ext_vector_type(4)));

#define MFMA16(a, b, c) __builtin_amdgcn_mfma_f32_16x16x32_bf16(a, b, c, 0, 0, 0)

constexpr int BB = 2, SS = 2048, DD = 4096, HH = 32, KVHH = 8, HDD = 128;
constexpr int QDIM = HH * HDD;     // 4096
constexpr int KVDIM = KVHH * HDD;  // 1024
constexpr int NQKV = QDIM + 2 * KVDIM;  // 6144
constexpr int LDX = NQKV;

__device__ inline void gload16(const bf16* g, bf16* l) {
    __builtin_amdgcn_global_load_lds((const __attribute__((address_space(1))) void*)g,
                                     (__attribute__((address_space(3))) void*)l, 16, 0, 0);
}

union U32BF2 { unsigned int u; bf16x2 v; };

// ---------------- fp32 -> bf16 convert (x) ----------------
__global__ __launch_bounds__(256) void cvt_bf16(const float* __restrict__ src,
                                                bf16* __restrict__ dst, int n4) {
    int i = blockIdx.x * 256 + threadIdx.x;
    if (i >= n4) return;
    float4 v = ((const float4*)src)[i];
    bf16x4 o;
    o[0] = (bf16)v.x; o[1] = (bf16)v.y; o[2] = (bf16)v.z; o[3] = (bf16)v.w;
    ((bf16x4*)dst)[i] = o;
}

// ---------------- weight transpose + fp32->bf16 ----------------
__global__ __launch_bounds__(256) void transpose_w(const float* __restrict__ src,
                                                   bf16* __restrict__ dst, int R, int C) {
    __shared__ bf16 t[32][33];
    int tx = threadIdx.x & 31, ty = threadIdx.x >> 5;
    int r0 = blockIdx.y * 32, c0 = blockIdx.x * 32;
#pragma unroll
    for (int i = 0; i < 4; i++)
        t[ty + i * 8][tx] = (bf16)src[(long)(r0 + ty + i * 8) * C + c0 + tx];
    __syncthreads();
#pragma unroll
    for (int i = 0; i < 4; i++)
        dst[(long)(c0 + ty + i * 8) * R + r0 + tx] = t[tx][ty + i * 8];
}

// ------------- V transpose from XQKV: Vt[((b*8+kvh)*128+hd)][pos] -------------
__global__ __launch_bounds__(256) void transpose_v(const bf16* __restrict__ XQKV,
                                                   bf16* __restrict__ Vt) {
    __shared__ bf16 t[32][33];
    int z = blockIdx.z, b = z >> 3, kvh = z & 7;
    int h0 = blockIdx.x * 32, p0 = blockIdx.y * 32;
    int tx = threadIdx.x & 31, ty = threadIdx.x >> 5;
#pragma unroll
    for (int i = 0; i < 4; i++)
        t[ty + i * 8][tx] = XQKV[(long)(b * SS + p0 + ty + i * 8) * LDX + QDIM + KVDIM +
                                 kvh * HDD + h0 + tx];
    __syncthreads();
#pragma unroll
    for (int i = 0; i < 4; i++)
        Vt[((long)(b * KVHH + kvh) * HDD + h0 + ty + i * 8) * SS + p0 + tx] =
            t[tx][ty + i * 8];
}

// ---- RoPE on Q section of XQKV, in place, uint-packed pairs ----
// NOTE: folds the attention scale 1/sqrt(128)*log2(e) into Q here, so QK^T
// scores come out of the MFMA pre-scaled (saves a v_mul per score in attn_k).
__global__ __launch_bounds__(256) void rope_q(bf16* __restrict__ X,
                                              const float* __restrict__ fc,
                                              const float* __restrict__ fs) {
    const float c2 = 0.08838834764831845f * 1.4426950408889634f;
    long t = (long)blockIdx.x * 256 + threadIdx.x;  // ((b*S+pos)*H + h)*64 + i2
    int i2 = (int)(t & 63);
    long u = t >> 6;
    int hh = (int)(u & 31);
    long bp = u >> 5;
    int pos = (int)(bp & (SS - 1));
    unsigned int* p = (unsigned int*)&X[bp * LDX + hh * HDD + 2 * i2];
    U32BF2 cv; cv.u = *p;
    float a = (float)cv.v[0], bb = (float)cv.v[1];
    float c = fc[pos * 64 + i2], s = fs[pos * 64 + i2];
    U32BF2 o;
    o.v[0] = (bf16)((a * c - bb * s) * c2);
    o.v[1] = (bf16)((a * s + bb * c) * c2);
    *p = o.u;
}

// ---- RoPE on K section of XQKV -> contiguous Kc[((b*8+kvh)*S+pos)*128+hd] ----
__global__ __launch_bounds__(256) void rope_kc(const bf16* __restrict__ X,
                                               const float* __restrict__ fc,
                                               const float* __restrict__ fs,
                                               bf16* __restrict__ Kc) {
    long t = (long)blockIdx.x * 256 + threadIdx.x;  // ((bk)*S+pos)*64 + i2
    int i2 = (int)(t & 63);
    long u = t >> 6;
    int pos = (int)(u & (SS - 1));
    int bk = (int)(u >> 11);
    int b = bk >> 3, kvh = bk & 7;
    const unsigned int* p =
        (const unsigned int*)&X[((long)(b * SS) + pos) * LDX + QDIM + kvh * HDD + 2 * i2];
    U32BF2 cv; cv.u = *p;
    float a = (float)cv.v[0], bb = (float)cv.v[1];
    float c = fc[pos * 64 + i2], s = fs[pos * 64 + i2];
    U32BF2 o;
    o.v[0] = (bf16)(a * c - bb * s);
    o.v[1] = (bf16)(a * s + bb * c);
    ((unsigned int*)Kc)[u * 64 + i2] = o.u;
}

// --------- suffix sums of V tiles from Vt: Suf[bk][t][hd] = sum_{j>=t*64} v_j ---------
__global__ __launch_bounds__(256) void sufv_k(const bf16* __restrict__ Vt,
                                              float* __restrict__ Suf) {
    __shared__ float ts[128][33];
    int bk = blockIdx.x;
    int hd = threadIdx.x & 127, tg = threadIdx.x >> 7;
    const bf16* row = Vt + ((long)bk * HDD + hd) * SS;
#pragma unroll
    for (int tt = 0; tt < 16; tt++) {
        int t = tg * 16 + tt;
        const bf16* p = row + t * 64;
        float s = 0.f;
#pragma unroll
        for (int j = 0; j < 8; j++) {
            bf16x8 v = *(const bf16x8*)&p[j * 8];
#pragma unroll
            for (int e = 0; e < 8; e++) s += (float)v[e];
        }
        ts[hd][t] = s;
    }
    __syncthreads();
    if (threadIdx.x < 128) {
        int h2 = threadIdx.x;
        float run = 0.f;
        Suf[((long)bk * 33 + 32) * HDD + h2] = 0.f;
        for (int t = 31; t >= 1; t--) {
            run += ts[h2][t];
            Suf[((long)bk * 33 + t) * HDD + h2] = run;
        }
    }
}

// ------- GEMM v2: 3-stage pipelined, BM=128 BN=256 BK=32, 8 waves (2Mx4N) -------
// T2: conflict-free LDS via chunk^(row&3) swizzle (inverse-swizzled global source,
//     linear gload_lds dest). T3/T4: prefetch tile t+2 during tile t; end-of-tile
//     s_waitcnt vmcnt(3) retires exactly tile t+1's loads while tile t+2's 3 loads
//     stay in flight across the barrier (never drains to 0 in steady state).
// T5: setprio around the 16-MFMA cluster. T1: XCD-bijective block swizzle.
// LDS = 3 x 24KB = 72KB -> 2 blocks/CU; __launch_bounds__(512,4) -> 4 waves/SIMD.
template <typename CT>
__global__ __launch_bounds__(512, 4) void gemm3s(const bf16* __restrict__ A,
                                                 const bf16* __restrict__ BT,
                                                 CT* __restrict__ C, int M, int N, int K) {
    constexpr int BM = 128, BN = 256, BK = 32;
    constexpr int ASZ = BM * BK;       // 4096 elems (8 KB)
    constexpr int BSZ = BN * BK;       // 8192 elems (16 KB)
    constexpr int STG = ASZ + BSZ;     // 12288 elems per stage
    __shared__ bf16 LDS[3 * STG];      // 72 KB
    const int tid = threadIdx.x;
    const int lane = tid & 63, w = tid >> 6;
    const int quad = lane >> 4, lcol = lane & 15;
    // XCD-aware bijective swizzle over the linear grid (nwg % 8 == 0 for our shapes)
    const int gx = gridDim.x;
    int bid = blockIdx.y * gx + blockIdx.x;
    const int cpx = (gx * gridDim.y) >> 3;
    bid = (bid & 7) * cpx + (bid >> 3);
    const int m0 = (bid / gx) * BM, n0 = (bid % gx) * BN;
    const int wm = (w >> 2) * 64, wn = (w & 3) * 64;
    // staging: LDS slot j=tid (A) holds phys chunk (j&3) of row j>>2; source must be
    // logical chunk c = (j&3)^(row&3)  [rule #21: linear dest, inverse-swz source]
    const int arow = tid >> 2, ac = (tid & 3) ^ (arow & 3);
    const int brow1 = (tid + 512) >> 2, bc1 = ((tid + 512) & 3) ^ (brow1 & 3);
    const bf16* gA = &A[(long)(m0 + arow) * K + ac * 8];
    const bf16* gB0 = &BT[(long)(n0 + arow) * K + ac * 8];
    const bf16* gB1 = &BT[(long)(n0 + brow1) * K + bc1 * 8];
    // LDS fragment-read bases (elements): row*32 + (quad^(lcol&3))*8, frag at +16*BK
    const int xs = (quad ^ (lcol & 3)) * 8;
    const int aro = (wm + lcol) * BK + xs;
    const int bro = (wn + lcol) * BK + xs;
    const int NKT = K / BK;
    f32x4 acc[4][4] = {};

    auto stage = [&](int t) {
        const int bo = (t % 3) * STG;
        const long ko = (long)t * BK;
        gload16(gA + ko, &LDS[bo + tid * 8]);
        gload16(gB0 + ko, &LDS[bo + ASZ + tid * 8]);
        gload16(gB1 + ko, &LDS[bo + ASZ + (512 + tid) * 8]);
    };

    stage(0);
    stage(1);
    asm volatile("s_waitcnt vmcnt(3)" ::: "memory");  // tile 0 landed
    __builtin_amdgcn_s_barrier();
    asm volatile("" ::: "memory");

    for (int t = 0; t < NKT; ++t) {
        const int bo = (t % 3) * STG;
        const bf16* la = &LDS[bo + aro];
        const bf16* lb = &LDS[bo + ASZ + bro];
        bf16x8 af[4], bfr[4];
#pragma unroll
        for (int i = 0; i < 4; i++) af[i] = *(const bf16x8*)&la[i * 16 * BK];
#pragma unroll
        for (int j = 0; j < 4; j++) bfr[j] = *(const bf16x8*)&lb[j * 16 * BK];
        if (t + 2 < NKT) stage(t + 2);
        asm volatile("s_waitcnt lgkmcnt(0)" ::: "memory");
        __builtin_amdgcn_sched_barrier(0);
        __builtin_amdgcn_s_setprio(1);
#pragma unroll
        for (int i = 0; i < 4; i++)
#pragma unroll
            for (int j = 0; j < 4; j++) acc[i][j] = MFMA16(af[i], bfr[j], acc[i][j]);
        __builtin_amdgcn_s_setprio(0);
        // retire tile t+1's loads; keep tile t+2's 3 loads in flight across the barrier
        if (t + 2 < NKT) asm volatile("s_waitcnt vmcnt(3)" ::: "memory");
        else             asm volatile("s_waitcnt vmcnt(0)" ::: "memory");
        __builtin_amdgcn_s_barrier();
        asm volatile("" ::: "memory");
    }
#pragma unroll
    for (int i = 0; i < 4; i++)
#pragma unroll
        for (int j = 0; j < 4; j++)
#pragma unroll
            for (int r = 0; r < 4; r++) {
                int row = m0 + wm + i * 16 + quad * 4 + r;
                int col = n0 + wn + j * 16 + lcol;
                C[(long)row * N + col] = (CT)acc[i][j][r];
            }
}

// -------- attention v5: 8 waves x 16 q-rows, swapped QK^T, in-register softmax --------
__global__ __launch_bounds__(512, 4) void attn_k(const bf16* __restrict__ XQKV,
                                                 const bf16* __restrict__ Kc,
                                                 const bf16* __restrict__ Vt,
                                                 const float* __restrict__ Suf,
                                                 bf16* __restrict__ AO) {
    __shared__ bf16 Ks[2][64 * 128];    // 16B-slot swizzled, double-buffered
    __shared__ bf16 Vs[2][128 * 64];    // 16B-slot swizzled, double-buffered
    __shared__ bf16 Pl[8][16 * 64];     // per-wave P roundtrip, XOR-swizzled rows
    const int tid = threadIdx.x;
    const int lane = tid & 63, w = tid >> 6;       // w in 0..7
    const int quad = lane >> 4, lcol = lane & 15;
    const int h = blockIdx.y, b = blockIdx.z;
    const int kvh = h >> 2;

    const bf16* KcB = Kc + (long)((b * KVHH + kvh) * SS) * HDD;
    const bf16* VtB = Vt + (long)((b * KVHH + kvh) * HDD) * SS;

    int kofs[2], vofs[2];
#pragma unroll
    for (int i = 0; i < 2; i++) {
        int j = i * 512 + tid;
        int p = j >> 4, cp = j & 15, c = cp ^ (p & 7);
        kofs[i] = p * HDD + c * 8;
        int r = j >> 3, cp2 = j & 7, cv = cp2 ^ (r & 7);
        vofs[i] = r * SS + cv * 8;
    }

    auto stageKV = [&](int buf, int kb0s) {
        bf16* ksb = &Ks[buf][0];
        bf16* vsb = &Vs[buf][0];
#pragma unroll
        for (int i = 0; i < 2; i++)
            gload16(KcB + (long)kb0s * HDD + kofs[i], &ksb[(i * 512 + tid) * 8]);
#pragma unroll
        for (int i = 0; i < 2; i++)
            gload16(VtB + (long)kb0s + vofs[i], &vsb[(i * 512 + tid) * 8]);
    };

    for (int rep = 0; rep < 2; rep++) {
        const int qc = rep == 0 ? 15 - (int)blockIdx.x : (int)blockIdx.x;
        const int qbase = qc * 128 + w * 16;
        const int NT = 2 * qc + 2;
        const int qpos = qbase + lcol;

        bf16x8 qf[4];
#pragma unroll
        for (int kc = 0; kc < 4; kc++)
            qf[kc] = *(const bf16x8*)&XQKV[((long)(b * SS) + qbase + lcol) * LDX +
                                           h * HDD + kc * 32 + quad * 8];
        f32x4 oacc[8] = {};
        float m2 = -1e30f, l = 0.f;

        stageKV(0, 0);
        asm volatile("s_waitcnt vmcnt(0)" ::: "memory");
        __builtin_amdgcn_s_barrier();

        int cur = 0;
        for (int kt = 0; kt < NT; kt++) {
            const int kb0 = kt * 64;
            stageKV(cur ^ 1, (kt + 1 < NT ? kt + 1 : kt) * 64);

            const bf16* KsC = &Ks[cur][0];
            const bf16* VsC = &Vs[cur][0];
            f32x4 sa[4] = {};
            __builtin_amdgcn_s_setprio(1);
#pragma unroll
            for (int ch = 0; ch < 4; ch++) {
                int p = ch * 16 + lcol;
#pragma unroll
                for (int kc = 0; kc < 4; kc++) {
                    int c = kc * 4 + quad;
                    bf16x8 kf = *(const bf16x8*)&KsC[(p * 16 + (c ^ (p & 7))) * 8];
                    sa[ch] = MFMA16(kf, qf[kc], sa[ch]);
                }
            }
            __builtin_amdgcn_s_setprio(0);
            if (kb0 + 63 > qbase) {
#pragma unroll
                for (int ch = 0; ch < 4; ch++)
#pragma unroll
                    for (int r = 0; r < 4; r++)
                        if (kb0 + ch * 16 + quad * 4 + r > qpos) sa[ch][r] = 0.f;
            }
            f32x4 mx = sa[0];
#pragma unroll
            for (int ch = 1; ch < 4; ch++)
#pragma unroll
                for (int r = 0; r < 4; r++) mx[r] = fmaxf(mx[r], sa[ch][r]);
            float mt = fmaxf(fmaxf(mx[0], mx[1]), fmaxf(mx[2], mx[3]));
            mt = fmaxf(mt, __shfl_xor(mt, 16, 64));
            mt = fmaxf(mt, __shfl_xor(mt, 32, 64));
            float mnew = fmaxf(m2, mt);
            float alpha = exp2f(m2 - mnew);
            m2 = mnew;
            float rs = 0.f;
            const int xm = (lcol & 7) << 3;
            bf16* plw = &Pl[w][0];
#pragma unroll
            for (int ch = 0; ch < 4; ch++) {
                bf16x4 pv;
#pragma unroll
                for (int r = 0; r < 4; r++) {
                    float e = exp2f(sa[ch][r] - mnew);
                    rs += e;
                    pv[r] = (bf16)e;
                }
                *(bf16x4*)&plw[lcol * 64 + ((ch * 16 + quad * 4) ^ xm)] = pv;
            }
            l = l * alpha + rs;
            bf16x8 pf0 = *(const bf16x8*)&plw[lcol * 64 + ((quad * 8) ^ xm)];
            bf16x8 pf1 = *(const bf16x8*)&plw[lcol * 64 + ((32 + quad * 8) ^ xm)];
            float a4[4];
#pragma unroll
            for (int r = 0; r < 4; r++)
                a4[r] = __shfl(alpha, (quad << 4) | (quad * 4 + r), 64);
            __builtin_amdgcn_s_setprio(1);
#pragma unroll
            for (int nj = 0; nj < 8; nj++) {
                int rr = nj * 16 + lcol;
                bf16x8 vf0 = *(const bf16x8*)&VsC[(rr * 8 + (quad ^ (rr & 7))) * 8];
                bf16x8 vf1 = *(const bf16x8*)&VsC[(rr * 8 + ((4 + quad) ^ (rr & 7))) * 8];
                f32x4 o = oacc[nj];
#pragma unroll
                for (int r = 0; r < 4; r++) o[r] *= a4[r];
                o = MFMA16(pf0, vf0, o);
                o = MFMA16(pf1, vf1, o);
                oacc[nj] = o;
            }
            __builtin_amdgcn_s_setprio(0);
            asm volatile("s_waitcnt vmcnt(0)" ::: "memory");
            __builtin_amdgcn_s_barrier();
            cur ^= 1;
        }
        l += __shfl_xor(l, 16, 64);
        l += __shfl_xor(l, 32, 64);
        const int cnt = SS - NT * 64;
        float mf = (cnt > 0) ? fmaxf(m2, 0.f) : m2;
        float so = exp2f(m2 - mf);
        float sm = exp2f(-mf);
        float rz = 1.f / (l * so + (float)cnt * sm);
        float so4[4], sm4[4], rz4[4];
#pragma unroll
        for (int r = 0; r < 4; r++) {
            int src = (quad << 4) | (quad * 4 + r);
            so4[r] = __shfl(so, src, 64);
            sm4[r] = __shfl(sm, src, 64);
            rz4[r] = __shfl(rz, src, 64);
        }
        const float* sufp = &Suf[((long)((b * KVHH + kvh) * 33) + NT) * HDD];
#pragma unroll
        for (int nj = 0; nj < 8; nj++) {
            float suf = sufp[nj * 16 + lcol];
#pragma unroll
            for (int r = 0; r < 4; r++) {
                float o = (oacc[nj][r] * so4[r] + sm4[r] * suf) * rz4[r];
                AO[((long)(b * SS) + qbase + quad * 4 + r) * QDIM + h * HDD +
                   nj * 16 + lcol] = (bf16)o;
            }
        }
    }
}

extern "C" void kernel_launch(void* const* d_in, const int* in_sizes, int n_in,
                              void* d_out, int out_size, void* d_ws, size_t ws_size,
                              hipStream_t stream) {
    const float* x  = (const float*)d_in[0];
    const float* fc = (const float*)d_in[1];
    const float* fs = (const float*)d_in[2];
    const float* wq = (const float*)d_in[4];
    const float* wk = (const float*)d_in[5];
    const float* wv = (const float*)d_in[6];
    const float* wo = (const float*)d_in[7];
    float* out = (float*)d_out;

    char* ws = (char*)d_ws;
    bf16* Wt   = (bf16*)ws; ws += (long)NQKV * DD * 2;             // 50.3 MB
    bf16* woT  = (bf16*)ws; ws += (long)DD * QDIM * 2;             // 33.6 MB
    bf16* XQKV = (bf16*)ws; ws += (long)BB * SS * NQKV * 2;        // 50.3 MB
    bf16* Vt   = (bf16*)ws; ws += (long)BB * KVHH * HDD * SS * 2;  // 8.4 MB
    bf16* Xb   = (bf16*)ws; ws += (long)BB * SS * DD * 2;          // 33.6 MB
    float* Suf = (float*)ws; ws += (long)BB * KVHH * 33 * HDD * 4; // 270 KB
    bf16* AO = Xb;            // Xb dead after QKV gemm
    bf16* Kc = Wt;            // Wt dead after QKV gemm (8.4 MB needed)

    const int M = BB * SS;  // 4096

    cvt_bf16<<<(DD * M / 4 + 255) / 256, 256, 0, stream>>>(x, Xb, DD * M / 4);

    transpose_w<<<dim3(QDIM / 32, DD / 32), 256, 0, stream>>>(wq, Wt, DD, QDIM);
    transpose_w<<<dim3(KVDIM / 32, DD / 32), 256, 0, stream>>>(wk, Wt + (long)QDIM * DD, DD, KVDIM);
    transpose_w<<<dim3(KVDIM / 32, DD / 32), 256, 0, stream>>>(wv, Wt + (long)(QDIM + KVDIM) * DD, DD, KVDIM);
    transpose_w<<<dim3(DD / 32, QDIM / 32), 256, 0, stream>>>(wo, woT, QDIM, DD);

    gemm3s<bf16><<<dim3(NQKV / 256, M / 128), 512, 0, stream>>>(Xb, Wt, XQKV, M, NQKV, DD);

    rope_q<<<(int)(((long)BB * SS * HH * 64) / 256), 256, 0, stream>>>(XQKV, fc, fs);
    rope_kc<<<(int)(((long)BB * KVHH * SS * 64) / 256), 256, 0, stream>>>(XQKV, fc, fs, Kc);

    transpose_v<<<dim3(HDD / 32, SS / 32, BB * KVHH), 256, 0, stream>>>(XQKV, Vt);
    sufv_k<<<BB * KVHH, 256, 0, stream>>>(Vt, Suf);

    attn_k<<<dim3(8, HH, BB), 512, 0, stream>>>(XQKV, Kc, Vt, Suf, AO);

    gemm3s<float><<<dim3(DD / 256, M / 128), 512, 0, stream>>>(AO, woT, out, M, DD, QDIM);
}

// Round 5
// 789.828 us; speedup vs baseline: 1.5420x; 1.0605x over previous
//
#include <hip/hip_runtime.h>
#include <hip/hip_bf16.h>

typedef __bf16 bf16;
typedef bf16 bf16x8 __attribute__((ext_vector_type(8)));
typedef bf16 bf16x4 __attribute__((ext_vector_type(4)));
typedef bf16 bf16x2 __attribute__((ext_vector_type(2)));
typedef float f32x4 __attribute__((ext_vector_type(4)));

#define MFMA16(a, b, c) __builtin_amdgcn_mfma_f32_16x16x32_bf16(a, b, c, 0, 0, 0)

constexpr int BB = 2, SS = 2048, DD = 4096, HH = 32, KVHH = 8, HDD = 128;
constexpr int QDIM = HH * HDD;     // 4096
constexpr int KVDIM = KVHH * HDD;  // 1024
constexpr int NQKV = QDIM + 2 * KVDIM;  // 6144
constexpr int LDX = NQKV;

__device__ inline void gload16(const bf16* g, bf16* l) {
    __builtin_amdgcn_global_load_lds((const __attribute__((address_space(1))) void*)g,
                                     (__attribute__((address_space(3))) void*)l, 16, 0, 0);
}

union U32BF2 { unsigned int u; bf16x2 v; };

// ---------------- fp32 -> bf16 convert (x) ----------------
__global__ __launch_bounds__(256) void cvt_bf16(const float* __restrict__ src,
                                                bf16* __restrict__ dst, int n4) {
    int i = blockIdx.x * 256 + threadIdx.x;
    if (i >= n4) return;
    float4 v = ((const float4*)src)[i];
    bf16x4 o;
    o[0] = (bf16)v.x; o[1] = (bf16)v.y; o[2] = (bf16)v.z; o[3] = (bf16)v.w;
    ((bf16x4*)dst)[i] = o;
}

// ---------------- weight transpose + fp32->bf16 ----------------
__global__ __launch_bounds__(256) void transpose_w(const float* __restrict__ src,
                                                   bf16* __restrict__ dst, int R, int C) {
    __shared__ bf16 t[32][33];
    int tx = threadIdx.x & 31, ty = threadIdx.x >> 5;
    int r0 = blockIdx.y * 32, c0 = blockIdx.x * 32;
#pragma unroll
    for (int i = 0; i < 4; i++)
        t[ty + i * 8][tx] = (bf16)src[(long)(r0 + ty + i * 8) * C + c0 + tx];
    __syncthreads();
#pragma unroll
    for (int i = 0; i < 4; i++)
        dst[(long)(c0 + ty + i * 8) * R + r0 + tx] = t[tx][ty + i * 8];
}

// ------------- V transpose from XQKV: Vt[((b*8+kvh)*128+hd)][pos] -------------
__global__ __launch_bounds__(256) void transpose_v(const bf16* __restrict__ XQKV,
                                                   bf16* __restrict__ Vt) {
    __shared__ bf16 t[32][33];
    int z = blockIdx.z, b = z >> 3, kvh = z & 7;
    int h0 = blockIdx.x * 32, p0 = blockIdx.y * 32;
    int tx = threadIdx.x & 31, ty = threadIdx.x >> 5;
#pragma unroll
    for (int i = 0; i < 4; i++)
        t[ty + i * 8][tx] = XQKV[(long)(b * SS + p0 + ty + i * 8) * LDX + QDIM + KVDIM +
                                 kvh * HDD + h0 + tx];
    __syncthreads();
#pragma unroll
    for (int i = 0; i < 4; i++)
        Vt[((long)(b * KVHH + kvh) * HDD + h0 + ty + i * 8) * SS + p0 + tx] =
            t[tx][ty + i * 8];
}

// ---- RoPE on Q section of XQKV, in place, uint-packed pairs ----
// NOTE: folds the attention scale 1/sqrt(128)*log2(e) into Q here, so QK^T
// scores come out of the MFMA pre-scaled (saves a v_mul per score in attn_k).
__global__ __launch_bounds__(256) void rope_q(bf16* __restrict__ X,
                                              const float* __restrict__ fc,
                                              const float* __restrict__ fs) {
    const float c2 = 0.08838834764831845f * 1.4426950408889634f;
    long t = (long)blockIdx.x * 256 + threadIdx.x;  // ((b*S+pos)*H + h)*64 + i2
    int i2 = (int)(t & 63);
    long u = t >> 6;
    int hh = (int)(u & 31);
    long bp = u >> 5;
    int pos = (int)(bp & (SS - 1));
    unsigned int* p = (unsigned int*)&X[bp * LDX + hh * HDD + 2 * i2];
    U32BF2 cv; cv.u = *p;
    float a = (float)cv.v[0], bb = (float)cv.v[1];
    float c = fc[pos * 64 + i2], s = fs[pos * 64 + i2];
    U32BF2 o;
    o.v[0] = (bf16)((a * c - bb * s) * c2);
    o.v[1] = (bf16)((a * s + bb * c) * c2);
    *p = o.u;
}

// ---- RoPE on K section of XQKV -> contiguous Kc[((b*8+kvh)*S+pos)*128+hd] ----
__global__ __launch_bounds__(256) void rope_kc(const bf16* __restrict__ X,
                                               const float* __restrict__ fc,
                                               const float* __restrict__ fs,
                                               bf16* __restrict__ Kc) {
    long t = (long)blockIdx.x * 256 + threadIdx.x;  // ((bk)*S+pos)*64 + i2
    int i2 = (int)(t & 63);
    long u = t >> 6;
    int pos = (int)(u & (SS - 1));
    int bk = (int)(u >> 11);
    int b = bk >> 3, kvh = bk & 7;
    const unsigned int* p =
        (const unsigned int*)&X[((long)(b * SS) + pos) * LDX + QDIM + kvh * HDD + 2 * i2];
    U32BF2 cv; cv.u = *p;
    float a = (float)cv.v[0], bb = (float)cv.v[1];
    float c = fc[pos * 64 + i2], s = fs[pos * 64 + i2];
    U32BF2 o;
    o.v[0] = (bf16)(a * c - bb * s);
    o.v[1] = (bf16)(a * s + bb * c);
    ((unsigned int*)Kc)[u * 64 + i2] = o.u;
}

// --------- suffix sums of V tiles from Vt: Suf[bk][t][hd] = sum_{j>=t*64} v_j ---------
__global__ __launch_bounds__(256) void sufv_k(const bf16* __restrict__ Vt,
                                              float* __restrict__ Suf) {
    __shared__ float ts[128][33];
    int bk = blockIdx.x;
    int hd = threadIdx.x & 127, tg = threadIdx.x >> 7;
    const bf16* row = Vt + ((long)bk * HDD + hd) * SS;
#pragma unroll
    for (int tt = 0; tt < 16; tt++) {
        int t = tg * 16 + tt;
        const bf16* p = row + t * 64;
        float s = 0.f;
#pragma unroll
        for (int j = 0; j < 8; j++) {
            bf16x8 v = *(const bf16x8*)&p[j * 8];
#pragma unroll
            for (int e = 0; e < 8; e++) s += (float)v[e];
        }
        ts[hd][t] = s;
    }
    __syncthreads();
    if (threadIdx.x < 128) {
        int h2 = threadIdx.x;
        float run = 0.f;
        Suf[((long)bk * 33 + 32) * HDD + h2] = 0.f;
        for (int t = 31; t >= 1; t--) {
            run += ts[h2][t];
            Suf[((long)bk * 33 + t) * HDD + h2] = run;
        }
    }
}

// ------- GEMM v3: 3-stage pipelined, BM=128 BN=256 BK=32, 8 waves (2Mx4N) -------
// Grid order: plain n-fastest (working set A+B+C ~134MB is L3-resident; XCD chunking
//   measured 3x over-fetch in r4 -> reverted per m160 "swizzle costs when L3-fit").
// T2: conflict-free LDS swizzle phys_chunk = logical ^ ((row>>1)&3): consecutive 8
//   lanes of a fragment read cover all 8 16B-slot-columns of the 128B bank span
//   (chunk = (row&1)<<2 | pc takes 0,4,1,5,2,6,3,7). Inverse-swz source, linear dest.
// T3/T4: prefetch tile t+2 during tile t; end-of-tile vmcnt(3) retires exactly tile
//   t+1's loads, keeps t+2's 3 loads in flight across the barrier (never drains to 0).
// T5: setprio around the 16-MFMA cluster.
template <typename CT>
__global__ __launch_bounds__(512, 4) void gemm3s(const bf16* __restrict__ A,
                                                 const bf16* __restrict__ BT,
                                                 CT* __restrict__ C, int M, int N, int K) {
    constexpr int BM = 128, BN = 256, BK = 32;
    constexpr int ASZ = BM * BK;       // 4096 elems (8 KB)
    constexpr int BSZ = BN * BK;       // 8192 elems (16 KB)
    constexpr int STG = ASZ + BSZ;     // 12288 elems per stage
    __shared__ bf16 LDS[3 * STG];      // 72 KB
    const int tid = threadIdx.x;
    const int lane = tid & 63, w = tid >> 6;
    const int quad = lane >> 4, lcol = lane & 15;
    const int m0 = blockIdx.y * BM, n0 = blockIdx.x * BN;
    const int wm = (w >> 2) * 64, wn = (w & 3) * 64;
    // staging: LDS slot j holds phys chunk (j&3) of row j>>2; phys = logical^((row>>1)&3)
    // so the global source reads logical chunk (j&3)^((j>>3)&3)  [involution]
    const int arow = tid >> 2, ac = (tid & 3) ^ ((tid >> 3) & 3);
    const int brow1 = (tid + 512) >> 2, bc1 = ((tid + 512) & 3) ^ (((tid + 512) >> 3) & 3);
    const bf16* gA = &A[(long)(m0 + arow) * K + ac * 8];
    const bf16* gB0 = &BT[(long)(n0 + arow) * K + ac * 8];
    const bf16* gB1 = &BT[(long)(n0 + brow1) * K + bc1 * 8];
    // fragment reads: logical chunk quad of row (wm|wn)+i*16+lcol -> phys quad^((lcol>>1)&3)
    // ((i*16)>>1 and (wm>>1) are both ≡0 mod 4, so row>>1&3 == lcol>>1&3)
    const int xs = (quad ^ ((lcol >> 1) & 3)) * 8;
    const int aro = (wm + lcol) * BK + xs;
    const int bro = (wn + lcol) * BK + xs;
    const int NKT = K / BK;
    f32x4 acc[4][4] = {};

    auto stage = [&](int t) {
        const int bo = (t % 3) * STG;
        const long ko = (long)t * BK;
        gload16(gA + ko, &LDS[bo + tid * 8]);
        gload16(gB0 + ko, &LDS[bo + ASZ + tid * 8]);
        gload16(gB1 + ko, &LDS[bo + ASZ + (512 + tid) * 8]);
    };

    stage(0);
    stage(1);
    asm volatile("s_waitcnt vmcnt(3)" ::: "memory");  // tile 0 landed
    __builtin_amdgcn_s_barrier();
    asm volatile("" ::: "memory");

    for (int t = 0; t < NKT; ++t) {
        const int bo = (t % 3) * STG;
        const bf16* la = &LDS[bo + aro];
        const bf16* lb = &LDS[bo + ASZ + bro];
        bf16x8 af[4], bfr[4];
#pragma unroll
        for (int i = 0; i < 4; i++) af[i] = *(const bf16x8*)&la[i * 16 * BK];
#pragma unroll
        for (int j = 0; j < 4; j++) bfr[j] = *(const bf16x8*)&lb[j * 16 * BK];
        if (t + 2 < NKT) stage(t + 2);
        asm volatile("s_waitcnt lgkmcnt(0)" ::: "memory");
        __builtin_amdgcn_sched_barrier(0);
        __builtin_amdgcn_s_setprio(1);
#pragma unroll
        for (int i = 0; i < 4; i++)
#pragma unroll
            for (int j = 0; j < 4; j++) acc[i][j] = MFMA16(af[i], bfr[j], acc[i][j]);
        __builtin_amdgcn_s_setprio(0);
        // retire tile t+1's loads; keep tile t+2's 3 loads in flight across the barrier
        if (t + 2 < NKT) asm volatile("s_waitcnt vmcnt(3)" ::: "memory");
        else             asm volatile("s_waitcnt vmcnt(0)" ::: "memory");
        __builtin_amdgcn_s_barrier();
        asm volatile("" ::: "memory");
    }
#pragma unroll
    for (int i = 0; i < 4; i++)
#pragma unroll
        for (int j = 0; j < 4; j++)
#pragma unroll
            for (int r = 0; r < 4; r++) {
                int row = m0 + wm + i * 16 + quad * 4 + r;
                int col = n0 + wn + j * 16 + lcol;
                C[(long)row * N + col] = (CT)acc[i][j][r];
            }
}

// -------- attention v5: 8 waves x 16 q-rows, swapped QK^T, in-register softmax --------
__global__ __launch_bounds__(512, 4) void attn_k(const bf16* __restrict__ XQKV,
                                                 const bf16* __restrict__ Kc,
                                                 const bf16* __restrict__ Vt,
                                                 const float* __restrict__ Suf,
                                                 bf16* __restrict__ AO) {
    __shared__ bf16 Ks[2][64 * 128];    // 16B-slot swizzled, double-buffered
    __shared__ bf16 Vs[2][128 * 64];    // 16B-slot swizzled, double-buffered
    __shared__ bf16 Pl[8][16 * 64];     // per-wave P roundtrip, XOR-swizzled rows
    const int tid = threadIdx.x;
    const int lane = tid & 63, w = tid >> 6;       // w in 0..7
    const int quad = lane >> 4, lcol = lane & 15;
    const int h = blockIdx.y, b = blockIdx.z;
    const int kvh = h >> 2;

    const bf16* KcB = Kc + (long)((b * KVHH + kvh) * SS) * HDD;
    const bf16* VtB = Vt + (long)((b * KVHH + kvh) * HDD) * SS;

    int kofs[2], vofs[2];
#pragma unroll
    for (int i = 0; i < 2; i++) {
        int j = i * 512 + tid;
        int p = j >> 4, cp = j & 15, c = cp ^ (p & 7);
        kofs[i] = p * HDD + c * 8;
        int r = j >> 3, cp2 = j & 7, cv = cp2 ^ (r & 7);
        vofs[i] = r * SS + cv * 8;
    }

    auto stageKV = [&](int buf, int kb0s) {
        bf16* ksb = &Ks[buf][0];
        bf16* vsb = &Vs[buf][0];
#pragma unroll
        for (int i = 0; i < 2; i++)
            gload16(KcB + (long)kb0s * HDD + kofs[i], &ksb[(i * 512 + tid) * 8]);
#pragma unroll
        for (int i = 0; i < 2; i++)
            gload16(VtB + (long)kb0s + vofs[i], &vsb[(i * 512 + tid) * 8]);
    };

    for (int rep = 0; rep < 2; rep++) {
        const int qc = rep == 0 ? 15 - (int)blockIdx.x : (int)blockIdx.x;
        const int qbase = qc * 128 + w * 16;
        const int NT = 2 * qc + 2;
        const int qpos = qbase + lcol;

        bf16x8 qf[4];
#pragma unroll
        for (int kc = 0; kc < 4; kc++)
            qf[kc] = *(const bf16x8*)&XQKV[((long)(b * SS) + qbase + lcol) * LDX +
                                           h * HDD + kc * 32 + quad * 8];
        f32x4 oacc[8] = {};
        float m2 = -1e30f, l = 0.f;

        stageKV(0, 0);
        asm volatile("s_waitcnt vmcnt(0)" ::: "memory");
        __builtin_amdgcn_s_barrier();

        int cur = 0;
        for (int kt = 0; kt < NT; kt++) {
            const int kb0 = kt * 64;
            stageKV(cur ^ 1, (kt + 1 < NT ? kt + 1 : kt) * 64);

            const bf16* KsC = &Ks[cur][0];
            const bf16* VsC = &Vs[cur][0];
            f32x4 sa[4] = {};
            __builtin_amdgcn_s_setprio(1);
#pragma unroll
            for (int ch = 0; ch < 4; ch++) {
                int p = ch * 16 + lcol;
#pragma unroll
                for (int kc = 0; kc < 4; kc++) {
                    int c = kc * 4 + quad;
                    bf16x8 kf = *(const bf16x8*)&KsC[(p * 16 + (c ^ (p & 7))) * 8];
                    sa[ch] = MFMA16(kf, qf[kc], sa[ch]);
                }
            }
            __builtin_amdgcn_s_setprio(0);
            if (kb0 + 63 > qbase) {
#pragma unroll
                for (int ch = 0; ch < 4; ch++)
#pragma unroll
                    for (int r = 0; r < 4; r++)
                        if (kb0 + ch * 16 + quad * 4 + r > qpos) sa[ch][r] = 0.f;
            }
            f32x4 mx = sa[0];
#pragma unroll
            for (int ch = 1; ch < 4; ch++)
#pragma unroll
                for (int r = 0; r < 4; r++) mx[r] = fmaxf(mx[r], sa[ch][r]);
            float mt = fmaxf(fmaxf(mx[0], mx[1]), fmaxf(mx[2], mx[3]));
            mt = fmaxf(mt, __shfl_xor(mt, 16, 64));
            mt = fmaxf(mt, __shfl_xor(mt, 32, 64));
            float mnew = fmaxf(m2, mt);
            float alpha = exp2f(m2 - mnew);
            m2 = mnew;
            float rs = 0.f;
            const int xm = (lcol & 7) << 3;
            bf16* plw = &Pl[w][0];
#pragma unroll
            for (int ch = 0; ch < 4; ch++) {
                bf16x4 pv;
#pragma unroll
                for (int r = 0; r < 4; r++) {
                    float e = exp2f(sa[ch][r] - mnew);
                    rs += e;
                    pv[r] = (bf16)e;
                }
                *(bf16x4*)&plw[lcol * 64 + ((ch * 16 + quad * 4) ^ xm)] = pv;
            }
            l = l * alpha + rs;
            bf16x8 pf0 = *(const bf16x8*)&plw[lcol * 64 + ((quad * 8) ^ xm)];
            bf16x8 pf1 = *(const bf16x8*)&plw[lcol * 64 + ((32 + quad * 8) ^ xm)];
            float a4[4];
#pragma unroll
            for (int r = 0; r < 4; r++)
                a4[r] = __shfl(alpha, (quad << 4) | (quad * 4 + r), 64);
            __builtin_amdgcn_s_setprio(1);
#pragma unroll
            for (int nj = 0; nj < 8; nj++) {
                int rr = nj * 16 + lcol;
                bf16x8 vf0 = *(const bf16x8*)&VsC[(rr * 8 + (quad ^ (rr & 7))) * 8];
                bf16x8 vf1 = *(const bf16x8*)&VsC[(rr * 8 + ((4 + quad) ^ (rr & 7))) * 8];
                f32x4 o = oacc[nj];
#pragma unroll
                for (int r = 0; r < 4; r++) o[r] *= a4[r];
                o = MFMA16(pf0, vf0, o);
                o = MFMA16(pf1, vf1, o);
                oacc[nj] = o;
            }
            __builtin_amdgcn_s_setprio(0);
            asm volatile("s_waitcnt vmcnt(0)" ::: "memory");
            __builtin_amdgcn_s_barrier();
            cur ^= 1;
        }
        l += __shfl_xor(l, 16, 64);
        l += __shfl_xor(l, 32, 64);
        const int cnt = SS - NT * 64;
        float mf = (cnt > 0) ? fmaxf(m2, 0.f) : m2;
        float so = exp2f(m2 - mf);
        float sm = exp2f(-mf);
        float rz = 1.f / (l * so + (float)cnt * sm);
        float so4[4], sm4[4], rz4[4];
#pragma unroll
        for (int r = 0; r < 4; r++) {
            int src = (quad << 4) | (quad * 4 + r);
            so4[r] = __shfl(so, src, 64);
            sm4[r] = __shfl(sm, src, 64);
            rz4[r] = __shfl(rz, src, 64);
        }
        const float* sufp = &Suf[((long)((b * KVHH + kvh) * 33) + NT) * HDD];
#pragma unroll
        for (int nj = 0; nj < 8; nj++) {
            float suf = sufp[nj * 16 + lcol];
#pragma unroll
            for (int r = 0; r < 4; r++) {
                float o = (oacc[nj][r] * so4[r] + sm4[r] * suf) * rz4[r];
                AO[((long)(b * SS) + qbase + quad * 4 + r) * QDIM + h * HDD +
                   nj * 16 + lcol] = (bf16)o;
            }
        }
    }
}

extern "C" void kernel_launch(void* const* d_in, const int* in_sizes, int n_in,
                              void* d_out, int out_size, void* d_ws, size_t ws_size,
                              hipStream_t stream) {
    const float* x  = (const float*)d_in[0];
    const float* fc = (const float*)d_in[1];
    const float* fs = (const float*)d_in[2];
    const float* wq = (const float*)d_in[4];
    const float* wk = (const float*)d_in[5];
    const float* wv = (const float*)d_in[6];
    const float* wo = (const float*)d_in[7];
    float* out = (float*)d_out;

    char* ws = (char*)d_ws;
    bf16* Wt   = (bf16*)ws; ws += (long)NQKV * DD * 2;             // 50.3 MB
    bf16* woT  = (bf16*)ws; ws += (long)DD * QDIM * 2;             // 33.6 MB
    bf16* XQKV = (bf16*)ws; ws += (long)BB * SS * NQKV * 2;        // 50.3 MB
    bf16* Vt   = (bf16*)ws; ws += (long)BB * KVHH * HDD * SS * 2;  // 8.4 MB
    bf16* Xb   = (bf16*)ws; ws += (long)BB * SS * DD * 2;          // 33.6 MB
    float* Suf = (float*)ws; ws += (long)BB * KVHH * 33 * HDD * 4; // 270 KB
    bf16* AO = Xb;            // Xb dead after QKV gemm
    bf16* Kc = Wt;            // Wt dead after QKV gemm (8.4 MB needed)

    const int M = BB * SS;  // 4096

    cvt_bf16<<<(DD * M / 4 + 255) / 256, 256, 0, stream>>>(x, Xb, DD * M / 4);

    transpose_w<<<dim3(QDIM / 32, DD / 32), 256, 0, stream>>>(wq, Wt, DD, QDIM);
    transpose_w<<<dim3(KVDIM / 32, DD / 32), 256, 0, stream>>>(wk, Wt + (long)QDIM * DD, DD, KVDIM);
    transpose_w<<<dim3(KVDIM / 32, DD / 32), 256, 0, stream>>>(wv, Wt + (long)(QDIM + KVDIM) * DD, DD, KVDIM);
    transpose_w<<<dim3(DD / 32, QDIM / 32), 256, 0, stream>>>(wo, woT, QDIM, DD);

    gemm3s<bf16><<<dim3(NQKV / 256, M / 128), 512, 0, stream>>>(Xb, Wt, XQKV, M, NQKV, DD);

    rope_q<<<(int)(((long)BB * SS * HH * 64) / 256), 256, 0, stream>>>(XQKV, fc, fs);
    rope_kc<<<(int)(((long)BB * KVHH * SS * 64) / 256), 256, 0, stream>>>(XQKV, fc, fs, Kc);

    transpose_v<<<dim3(HDD / 32, SS / 32, BB * KVHH), 256, 0, stream>>>(XQKV, Vt);
    sufv_k<<<BB * KVHH, 256, 0, stream>>>(Vt, Suf);

    attn_k<<<dim3(8, HH, BB), 512, 0, stream>>>(XQKV, Kc, Vt, Suf, AO);

    gemm3s<float><<<dim3(DD / 256, M / 128), 512, 0, stream>>>(AO, woT, out, M, DD, QDIM);
}